// Round 3
// baseline (330.446 us; speedup 1.0000x reference)
//
#include <hip/hip_runtime.h>
#include <hip/hip_bf16.h>

#define B_ 8
#define S_ 4096
#define HID_ 640
#define KV_ 77
#define AU_ 16
#define CROSS_ 768
#define HEADS_ 10
#define DH_ 64
#define SCALE_ 0.125f

using f32x4 = __attribute__((ext_vector_type(4))) float;
using bf16x8 = __attribute__((ext_vector_type(8))) short;

__device__ __forceinline__ unsigned short f2bf(float f) {
  unsigned u = __float_as_uint(f);
  u = (u + 0x7fffu + ((u >> 16) & 1u)) >> 16;
  return (unsigned short)u;
}

// ---------------------------------------------------------------- prior table
__global__ __launch_bounds__(256) void prior_k(float* prior) {
  int i = blockIdx.x * 256 + threadIdx.x;
  if (i < S_) {
    int yy = i >> 6, xx = i & 63;
    float lx = -1.f + 2.f * (float)xx / 63.f;
    float ly = -1.f + 2.f * (float)yy / 63.f;
    prior[i] = __expf(-(lx * lx + ly * ly) * (1.0f / 0.605f));
  }
}

// ---------------------------------------------------------------- GEMM core
// C[m0+128, n0+128] = A[M,K] @ B[K,N]; A f32 or bf16(short), B f32.
// Output bf16 (EPI=false) or f32 with bias+residual (EPI=true).
template <bool ABF16, bool EPI>
__device__ __forceinline__ void gemm_dev(const void* Aptr, const float* Bw,
                                         void* Cout, const float* bias,
                                         const float* resid, int M, int K,
                                         int N, int m0, int n0) {
  __shared__ short Al[128][72];
  __shared__ short Bl[128][72];
  const int t = threadIdx.x;
  const int lane = t & 63;
  const int wave = t >> 6;
  const int l15 = lane & 15, lg = lane >> 4;
  const int wr = (wave >> 1) * 64, wc = (wave & 1) * 64;

  f32x4 z4 = {0.f, 0.f, 0.f, 0.f};
  f32x4 acc[4][4];
#pragma unroll
  for (int i = 0; i < 4; ++i)
#pragma unroll
    for (int j = 0; j < 4; ++j) acc[i][j] = z4;

  for (int k0 = 0; k0 < K; k0 += 64) {
    // ---- stage A tile [128][64] -> bf16 LDS
    if (!ABF16) {
      const float* A32 = (const float*)Aptr;
#pragma unroll
      for (int j = 0; j < 8; ++j) {
        int i = t + j * 256;
        int r = i >> 4, q = i & 15;
        int row = m0 + r;
        float4 v = {0.f, 0.f, 0.f, 0.f};
        if (row < M) v = *(const float4*)(A32 + (size_t)row * K + k0 + q * 4);
        short4 s;
        s.x = (short)f2bf(v.x);
        s.y = (short)f2bf(v.y);
        s.z = (short)f2bf(v.z);
        s.w = (short)f2bf(v.w);
        *(short4*)&Al[r][q * 4] = s;
      }
    } else {
      // FIXED (round 2): full coverage — 128 rows x 64 shorts = 1024 int4s.
      // Previous version only wrote 8 of every 16 shorts (stale LDS -> garbage).
      const short* A16 = (const short*)Aptr;
#pragma unroll
      for (int j = 0; j < 4; ++j) {
        int i = t + j * 256;
        int r = i >> 3, q = i & 7;
        int row = m0 + r;
        int4 v = {0, 0, 0, 0};
        if (row < M) v = *(const int4*)(A16 + (size_t)row * K + k0 + q * 8);
        *(int4*)&Al[r][q * 8] = v;
      }
    }
    // ---- stage B tile [64][128] transposed -> Bl[n][k]
#pragma unroll
    for (int j = 0; j < 4; ++j) {
      int g = t + j * 256;
      int n = g & 127, kg = g >> 7;
      const float* bp = Bw + (size_t)(k0 + kg * 8) * N + n0 + n;
      unsigned sh[8];
#pragma unroll
      for (int i2 = 0; i2 < 8; ++i2) sh[i2] = f2bf(bp[(size_t)i2 * N]);
      int4 w;
      w.x = (int)(sh[0] | (sh[1] << 16));
      w.y = (int)(sh[2] | (sh[3] << 16));
      w.z = (int)(sh[4] | (sh[5] << 16));
      w.w = (int)(sh[6] | (sh[7] << 16));
      *(int4*)&Bl[n][kg * 8] = w;
    }
    __syncthreads();
#pragma unroll
    for (int ks = 0; ks < 64; ks += 32) {
      bf16x8 af[4], bfr[4];
#pragma unroll
      for (int mi = 0; mi < 4; ++mi)
        af[mi] = *(const bf16x8*)&Al[wr + mi * 16 + l15][ks + lg * 8];
#pragma unroll
      for (int ni = 0; ni < 4; ++ni)
        bfr[ni] = *(const bf16x8*)&Bl[wc + ni * 16 + l15][ks + lg * 8];
#pragma unroll
      for (int mi = 0; mi < 4; ++mi)
#pragma unroll
        for (int ni = 0; ni < 4; ++ni)
          acc[mi][ni] = __builtin_amdgcn_mfma_f32_16x16x32_bf16(
              af[mi], bfr[ni], acc[mi][ni], 0, 0, 0);
    }
    __syncthreads();
  }
  // ---- epilogue
#pragma unroll
  for (int mi = 0; mi < 4; ++mi) {
#pragma unroll
    for (int j = 0; j < 4; ++j) {
      int row = m0 + wr + mi * 16 + lg * 4 + j;
      if (row >= M) continue;
#pragma unroll
      for (int ni = 0; ni < 4; ++ni) {
        int col = n0 + wc + ni * 16 + l15;
        size_t idx = (size_t)row * N + col;
        float val = acc[mi][ni][j];
        if (EPI) {
          ((float*)Cout)[idx] = val + bias[col] + resid[idx];
        } else {
          ((short*)Cout)[idx] = (short)f2bf(val);
        }
      }
    }
  }
}

__global__ __launch_bounds__(256) void gemm_q_k(const float* A, const float* Bw,
                                                short* C, int M, int K, int N) {
  gemm_dev<false, false>(A, Bw, C, nullptr, nullptr, M, K, N,
                         blockIdx.x * 128, blockIdx.y * 128);
}

__global__ __launch_bounds__(256) void gemm_out_k(const short* A,
                                                  const float* Bw, float* C,
                                                  const float* bias,
                                                  const float* resid, int M,
                                                  int K, int N) {
  gemm_dev<true, true>(A, Bw, C, bias, resid, M, K, N, blockIdx.x * 128,
                       blockIdx.y * 128);
}

__global__ __launch_bounds__(256) void proj4_k(const float* enc,
                                               const float* au, const float* Wk,
                                               const float* Wv,
                                               const float* Wauk,
                                               const float* Wauv, short* Kb,
                                               short* Vb, short* AKb,
                                               short* AVb) {
  int z = blockIdx.z;
  const float* A = (z < 2) ? enc : au;
  const float* Bw = (z == 0) ? Wk : (z == 1) ? Wv : (z == 2) ? Wauk : Wauv;
  short* O = (z == 0) ? Kb : (z == 1) ? Vb : (z == 2) ? AKb : AVb;
  int M = (z < 2) ? (B_ * KV_) : (B_ * AU_);
  if ((int)blockIdx.x * 128 >= M) return;
  gemm_dev<false, false>(A, Bw, O, nullptr, nullptr, M, CROSS_, HID_,
                         blockIdx.x * 128, blockIdx.y * 128);
}

// ---------------------------------------------------------------- attention
// NOTE: Ob may alias Qb (in-place). Block (q0,h,b) reads exactly the Q region
// (rows b*S+q0..+64, cols h*64..+64) that it later writes; all Q reads finish
// before the post-staging __syncthreads, all writes happen in the epilogue.
// No other block touches that region -> race-free.
__global__ __launch_bounds__(256) void attn_k(const short* Qb, const short* Kb,
                                              const short* Vb, const short* AKb,
                                              const short* AVb,
                                              const float* prior, short* Ob,
                                              const float* temp,
                                              const float* gate) {
  __shared__ short Qt[64][72];
  __shared__ short Kl[80][72];
  __shared__ short Vt[64][104];
  __shared__ short Pl[64][104];
  __shared__ short AUKl[16][72];
  __shared__ short AUVt[64][40];
  __shared__ short Ml[64][40];

  const int t = threadIdx.x;
  const int lane = t & 63, wave = t >> 6;
  const int l15 = lane & 15, lg = lane >> 4;
  const int q0 = blockIdx.x * 64;
  const int h = blockIdx.y;
  const int b = blockIdx.z;
  const int rw = wave * 16;

  // zero buffers that rely on zero padding
  {
    int* p = (int*)&Vt[0][0];
    for (int i = t; i < 64 * 104 / 2; i += 256) p[i] = 0;
    p = (int*)&Pl[0][0];
    for (int i = t; i < 64 * 104 / 2; i += 256) p[i] = 0;
    p = (int*)&AUVt[0][0];
    for (int i = t; i < 64 * 40 / 2; i += 256) p[i] = 0;
    p = (int*)&Ml[0][0];
    for (int i = t; i < 64 * 40 / 2; i += 256) p[i] = 0;
    p = (int*)&Kl[77][0];
    for (int i = t; i < 3 * 72 / 2; i += 256) p[i] = 0;
  }
  __syncthreads();

  // stage Q [64][64]
#pragma unroll
  for (int j = 0; j < 2; ++j) {
    int i = t + j * 256;
    int r = i >> 3, c8 = i & 7;
    *(int4*)&Qt[r][c8 * 8] =
        *(const int4*)(Qb + (size_t)(b * S_ + q0 + r) * HID_ + h * DH_ +
                       c8 * 8);
  }
  // stage K [77][64]
#pragma unroll
  for (int j = 0; j < 3; ++j) {
    int i = t + j * 256;
    if (i < KV_ * 8) {
      int r = i >> 3, c8 = i & 7;
      *(int4*)&Kl[r][c8 * 8] =
          *(const int4*)(Kb + (size_t)(b * KV_ + r) * HID_ + h * DH_ + c8 * 8);
    }
  }
  // stage V transposed -> Vt[d][kv]
  for (int i = t; i < KV_ * DH_; i += 256) {
    int d = i & 63, kv = i >> 6;
    Vt[d][kv] = Vb[(size_t)(b * KV_ + kv) * HID_ + h * DH_ + d];
  }
  // stage AUK [16][64]
  if (t < AU_ * 8) {
    int r = t >> 3, c8 = t & 7;
    *(int4*)&AUKl[r][c8 * 8] =
        *(const int4*)(AKb + (size_t)(b * AU_ + r) * HID_ + h * DH_ + c8 * 8);
  }
  // stage AUV transposed -> AUVt[d][au]
  for (int i = t; i < AU_ * DH_; i += 256) {
    int d = i & 63, a = i >> 6;
    AUVt[d][a] = AVb[(size_t)(b * AU_ + a) * HID_ + h * DH_ + d];
  }
  __syncthreads();

  // QK^T (64x80) and AU scores (64x16)
  f32x4 z4 = {0.f, 0.f, 0.f, 0.f};
  f32x4 accS[5], accA = z4;
#pragma unroll
  for (int c = 0; c < 5; ++c) accS[c] = z4;
#pragma unroll
  for (int ks = 0; ks < 64; ks += 32) {
    bf16x8 aq = *(const bf16x8*)&Qt[rw + l15][ks + lg * 8];
#pragma unroll
    for (int c = 0; c < 5; ++c) {
      bf16x8 bk = *(const bf16x8*)&Kl[c * 16 + l15][ks + lg * 8];
      accS[c] = __builtin_amdgcn_mfma_f32_16x16x32_bf16(aq, bk, accS[c], 0, 0, 0);
    }
    bf16x8 ba = *(const bf16x8*)&AUKl[l15][ks + lg * 8];
    accA = __builtin_amdgcn_mfma_f32_16x16x32_bf16(aq, ba, accA, 0, 0, 0);
  }

  const float invT = 1.f / (fabsf(temp[0]) + 1e-6f);
#pragma unroll
  for (int j = 0; j < 4; ++j) {
    float v[5];
    float m = -1e30f;
#pragma unroll
    for (int c = 0; c < 5; ++c) {
      int col = c * 16 + l15;
      v[c] = (col < KV_) ? accS[c][j] * SCALE_ : -1e30f;
      m = fmaxf(m, v[c]);
    }
#pragma unroll
    for (int off = 1; off < 16; off <<= 1) m = fmaxf(m, __shfl_xor(m, off));
    float p[5];
    float s = 0.f;
#pragma unroll
    for (int c = 0; c < 5; ++c) {
      p[c] = (v[c] > -1e29f) ? __expf(v[c] - m) : 0.f;
      s += p[c];
    }
#pragma unroll
    for (int off = 1; off < 16; off <<= 1) s += __shfl_xor(s, off);
    float inv = 1.f / s;
    int r = rw + lg * 4 + j;
#pragma unroll
    for (int c = 0; c < 5; ++c) Pl[r][c * 16 + l15] = (short)f2bf(p[c] * inv);
    // AU mask
    float as = accA[j] * SCALE_ * invT;
    float sg = 1.f / (1.f + __expf(-as));
    float mv = sg * prior[q0 + r] * 0.9f + 0.1f;
    Ml[r][l15] = (short)f2bf(mv);
  }
  __syncthreads();

  // PV (K=96 incl. zero pad) and mask @ AUV (K=32 incl. zero pad)
  f32x4 accO[4], accAO[4];
#pragma unroll
  for (int c = 0; c < 4; ++c) {
    accO[c] = z4;
    accAO[c] = z4;
  }
#pragma unroll
  for (int kk = 0; kk < 96; kk += 32) {
    bf16x8 ap = *(const bf16x8*)&Pl[rw + l15][kk + lg * 8];
#pragma unroll
    for (int c = 0; c < 4; ++c) {
      bf16x8 bv = *(const bf16x8*)&Vt[c * 16 + l15][kk + lg * 8];
      accO[c] = __builtin_amdgcn_mfma_f32_16x16x32_bf16(ap, bv, accO[c], 0, 0, 0);
    }
  }
  {
    bf16x8 am = *(const bf16x8*)&Ml[rw + l15][lg * 8];
#pragma unroll
    for (int c = 0; c < 4; ++c) {
      bf16x8 bv = *(const bf16x8*)&AUVt[c * 16 + l15][lg * 8];
      accAO[c] =
          __builtin_amdgcn_mfma_f32_16x16x32_bf16(am, bv, accAO[c], 0, 0, 0);
    }
  }
  const float g = gate[0];  // AU_SCALE = 1
#pragma unroll
  for (int c = 0; c < 4; ++c)
#pragma unroll
    for (int j = 0; j < 4; ++j) {
      int r = rw + lg * 4 + j;
      float val = accO[c][j] + g * accAO[c][j];
      Ob[(size_t)(b * S_ + q0 + r) * HID_ + h * DH_ + c * 16 + l15] =
          (short)f2bf(val);
    }
}

// ---------------------------------------------------------------- launcher
extern "C" void kernel_launch(void* const* d_in, const int* in_sizes, int n_in,
                              void* d_out, int out_size, void* d_ws,
                              size_t ws_size, hipStream_t stream) {
  const float* hs = (const float*)d_in[0];
  const float* enc = (const float*)d_in[1];
  const float* au = (const float*)d_in[2];
  const float* Wq = (const float*)d_in[3];
  const float* Wk = (const float*)d_in[4];
  const float* Wv = (const float*)d_in[5];
  const float* Wauk = (const float*)d_in[6];
  const float* Wauv = (const float*)d_in[7];
  const float* Wout = (const float*)d_in[8];
  const float* bout = (const float*)d_in[9];
  const float* temp = (const float*)d_in[10];
  const float* gate = (const float*)d_in[11];
  float* out = (float*)d_out;
  char* ws = (char*)d_ws;

  const size_t szK = (size_t)B_ * KV_ * HID_ * 2;   // 788480
  const size_t szAU = (size_t)B_ * AU_ * HID_ * 2;  // 163840

  size_t off = 0;
  float* prior = (float*)(ws + off);
  off += 16384;
  short* Kbf = (short*)(ws + off);
  off += szK;
  short* Vbf = (short*)(ws + off);
  off += szK;
  short* AUKbf = (short*)(ws + off);
  off += szAU;
  short* AUVbf = (short*)(ws + off);
  off += szAU;
  short* Qbf = (short*)(ws + off);  // 41.94 MB; total ws need = 43.88 MB
  short* Abf = Qbf;                 // ALIAS: attn overwrites Q in place (safe)

  prior_k<<<16, 256, 0, stream>>>(prior);
  proj4_k<<<dim3(5, 5, 4), 256, 0, stream>>>(enc, au, Wk, Wv, Wauk, Wauv, Kbf,
                                             Vbf, AUKbf, AUVbf);
  gemm_q_k<<<dim3(256, 5), 256, 0, stream>>>(hs, Wq, Qbf, B_ * S_, HID_, HID_);
  attn_k<<<dim3(64, HEADS_, B_), 256, 0, stream>>>(Qbf, Kbf, Vbf, AUKbf, AUVbf,
                                                   prior, Abf, temp, gate);
  gemm_out_k<<<dim3(256, 5), 256, 0, stream>>>(Abf, Wout, out, bout, hs,
                                               B_ * S_, HID_, HID_);
}

// Round 4
// 315.657 us; speedup vs baseline: 1.0469x; 1.0469x over previous
//
#include <hip/hip_runtime.h>
#include <hip/hip_bf16.h>

#define B_ 8
#define S_ 4096
#define HID_ 640
#define KV_ 77
#define AU_ 16
#define CROSS_ 768
#define HEADS_ 10
#define DH_ 64
#define SCALE_ 0.125f

using f32x4 = __attribute__((ext_vector_type(4))) float;
using bf16x8 = __attribute__((ext_vector_type(8))) short;

__device__ __forceinline__ short bfc(float f) {
  __hip_bfloat16 h = __float2bfloat16(f);
  return __builtin_bit_cast(short, h);
}

// ---------------------------------------------------------------- prior table
__global__ __launch_bounds__(256) void prior_k(float* prior) {
  int i = blockIdx.x * 256 + threadIdx.x;
  if (i < S_) {
    int yy = i >> 6, xx = i & 63;
    float lx = -1.f + 2.f * (float)xx / 63.f;
    float ly = -1.f + 2.f * (float)yy / 63.f;
    prior[i] = __expf(-(lx * lx + ly * ly) * (1.0f / 0.605f));
  }
}

// ------------------------------------------------- weight transpose + convert
// W [K][640] f32 row-major  ->  Wt [640][K] bf16 row-major.
__global__ __launch_bounds__(256) void wprep_k(
    const float* Wq, const float* Wk, const float* Wv, const float* Wauk,
    const float* Wauv, const float* Wout, short* Wqt, short* Wkt, short* Wvt,
    short* Waukt, short* Wauvt, short* Woutt) {
  const float* W;
  short* Wt;
  int K;
  switch (blockIdx.z) {
    case 0: W = Wq;   Wt = Wqt;   K = 640; break;
    case 1: W = Wk;   Wt = Wkt;   K = 768; break;
    case 2: W = Wv;   Wt = Wvt;   K = 768; break;
    case 3: W = Wauk; Wt = Waukt; K = 768; break;
    case 4: W = Wauv; Wt = Wauvt; K = 768; break;
    default: W = Wout; Wt = Woutt; K = 640; break;
  }
  int kt = blockIdx.y * 64, nt = blockIdx.x * 64;
  if (kt >= K) return;
  __shared__ short Tl[64][72];
  const int t = threadIdx.x;
#pragma unroll
  for (int j = 0; j < 16; ++j) {
    int i = t + j * 256;
    int r = i >> 6, c = i & 63;
    Tl[c][r] = bfc(W[(size_t)(kt + r) * 640 + nt + c]);
  }
  __syncthreads();
#pragma unroll
  for (int j = 0; j < 2; ++j) {
    int i = t + j * 256;
    int nl = i >> 3, c = i & 7;
    *(int4*)&Wt[(size_t)(nt + nl) * K + kt + c * 8] = *(int4*)&Tl[nl][c * 8];
  }
}

// ---------------------------------------------------------------- GEMM core
// C[m0+128, n0+128] = A[M,K] @ B[K,N]; A f32 or bf16(short);
// Bt = pre-transposed bf16 [N][K]. Output bf16 (EPI=false) or f32 with
// bias+residual (EPI=true).
template <bool ABF16, bool EPI>
__device__ __forceinline__ void gemm_dev(const void* Aptr, const short* Bt,
                                         void* Cout, const float* bias,
                                         const float* resid, int M, int K,
                                         int N, int m0, int n0) {
  __shared__ short Al[128][72];
  __shared__ short Bl[128][72];
  const int t = threadIdx.x;
  const int lane = t & 63;
  const int wave = t >> 6;
  const int l15 = lane & 15, lg = lane >> 4;
  const int wr = (wave >> 1) * 64, wc = (wave & 1) * 64;

  f32x4 z4 = {0.f, 0.f, 0.f, 0.f};
  f32x4 acc[4][4];
#pragma unroll
  for (int i = 0; i < 4; ++i)
#pragma unroll
    for (int j = 0; j < 4; ++j) acc[i][j] = z4;

  for (int k0 = 0; k0 < K; k0 += 64) {
    // ---- stage A tile [128][64] -> bf16 LDS
    if (!ABF16) {
      const float* A32 = (const float*)Aptr;
#pragma unroll
      for (int j = 0; j < 8; ++j) {
        int i = t + j * 256;
        int r = i >> 4, q = i & 15;
        int row = m0 + r;
        float4 v = {0.f, 0.f, 0.f, 0.f};
        if (row < M) v = *(const float4*)(A32 + (size_t)row * K + k0 + q * 4);
        short4 s;
        s.x = bfc(v.x);
        s.y = bfc(v.y);
        s.z = bfc(v.z);
        s.w = bfc(v.w);
        *(short4*)&Al[r][q * 4] = s;
      }
    } else {
      const short* A16 = (const short*)Aptr;
#pragma unroll
      for (int j = 0; j < 4; ++j) {
        int i = t + j * 256;
        int r = i >> 3, q = i & 7;
        int row = m0 + r;
        int4 v = {0, 0, 0, 0};
        if (row < M) v = *(const int4*)(A16 + (size_t)row * K + k0 + q * 8);
        *(int4*)&Al[r][q * 8] = v;
      }
    }
    // ---- stage B tile: Bl[n][k] <- Bt[n0+n][k0..k0+64), contiguous copies
#pragma unroll
    for (int j = 0; j < 4; ++j) {
      int i = t + j * 256;
      int row = i >> 3, c = i & 7;
      *(int4*)&Bl[row][c * 8] =
          *(const int4*)(Bt + (size_t)(n0 + row) * K + k0 + c * 8);
    }
    __syncthreads();
#pragma unroll
    for (int ks = 0; ks < 64; ks += 32) {
      bf16x8 af[4], bfr[4];
#pragma unroll
      for (int mi = 0; mi < 4; ++mi)
        af[mi] = *(const bf16x8*)&Al[wr + mi * 16 + l15][ks + lg * 8];
#pragma unroll
      for (int ni = 0; ni < 4; ++ni)
        bfr[ni] = *(const bf16x8*)&Bl[wc + ni * 16 + l15][ks + lg * 8];
#pragma unroll
      for (int mi = 0; mi < 4; ++mi)
#pragma unroll
        for (int ni = 0; ni < 4; ++ni)
          acc[mi][ni] = __builtin_amdgcn_mfma_f32_16x16x32_bf16(
              af[mi], bfr[ni], acc[mi][ni], 0, 0, 0);
    }
    __syncthreads();
  }
  // ---- epilogue
#pragma unroll
  for (int mi = 0; mi < 4; ++mi) {
#pragma unroll
    for (int j = 0; j < 4; ++j) {
      int row = m0 + wr + mi * 16 + lg * 4 + j;
      if (row >= M) continue;
#pragma unroll
      for (int ni = 0; ni < 4; ++ni) {
        int col = n0 + wc + ni * 16 + l15;
        size_t idx = (size_t)row * N + col;
        float val = acc[mi][ni][j];
        if (EPI) {
          ((float*)Cout)[idx] = val + bias[col] + resid[idx];
        } else {
          ((short*)Cout)[idx] = bfc(val);
        }
      }
    }
  }
}

__global__ __launch_bounds__(256) void gemm_q_k(const float* A, const short* Bt,
                                                short* C, int M, int K, int N) {
  gemm_dev<false, false>(A, Bt, C, nullptr, nullptr, M, K, N,
                         blockIdx.x * 128, blockIdx.y * 128);
}

__global__ __launch_bounds__(256) void gemm_out_k(const short* A,
                                                  const short* Bt, float* C,
                                                  const float* bias,
                                                  const float* resid, int M,
                                                  int K, int N) {
  gemm_dev<true, true>(A, Bt, C, bias, resid, M, K, N, blockIdx.x * 128,
                       blockIdx.y * 128);
}

__global__ __launch_bounds__(256) void proj4_k(const float* enc,
                                               const float* au,
                                               const short* Wkt,
                                               const short* Wvt,
                                               const short* Waukt,
                                               const short* Wauvt, short* Kb,
                                               short* Vb, short* AKb,
                                               short* AVb) {
  int z = blockIdx.z;
  const float* A = (z < 2) ? enc : au;
  const short* Bt = (z == 0) ? Wkt : (z == 1) ? Wvt : (z == 2) ? Waukt : Wauvt;
  short* O = (z == 0) ? Kb : (z == 1) ? Vb : (z == 2) ? AKb : AVb;
  int M = (z < 2) ? (B_ * KV_) : (B_ * AU_);
  if ((int)blockIdx.x * 128 >= M) return;
  gemm_dev<false, false>(A, Bt, O, nullptr, nullptr, M, CROSS_, HID_,
                         blockIdx.x * 128, blockIdx.y * 128);
}

// ---------------------------------------------------------------- attention
// NOTE: Ob may alias Qb (in-place) — block (q0,h,b) reads exactly the Q region
// it later writes; reads complete before the staging barrier. Race-free.
__global__ __launch_bounds__(256) void attn_k(const short* Qb, const short* Kb,
                                              const short* Vb, const short* AKb,
                                              const short* AVb,
                                              const float* prior, short* Ob,
                                              const float* temp,
                                              const float* gate) {
  __shared__ short Qt[64][72];
  __shared__ short Kl[80][72];
  __shared__ short Vt[64][104];
  __shared__ short Pl[64][104];
  __shared__ short AUKl[16][72];
  __shared__ short AUVt[64][40];
  __shared__ short Ml[64][40];

  const int t = threadIdx.x;
  const int lane = t & 63, wave = t >> 6;
  const int l15 = lane & 15, lg = lane >> 4;
  const int q0 = blockIdx.x * 64;
  const int h = blockIdx.y;
  const int b = blockIdx.z;
  const int rw = wave * 16;

  // zero buffers that rely on zero padding
  {
    int* p = (int*)&Vt[0][0];
    for (int i = t; i < 64 * 104 / 2; i += 256) p[i] = 0;
    p = (int*)&Pl[0][0];
    for (int i = t; i < 64 * 104 / 2; i += 256) p[i] = 0;
    p = (int*)&AUVt[0][0];
    for (int i = t; i < 64 * 40 / 2; i += 256) p[i] = 0;
    p = (int*)&Ml[0][0];
    for (int i = t; i < 64 * 40 / 2; i += 256) p[i] = 0;
    p = (int*)&Kl[77][0];
    for (int i = t; i < 3 * 72 / 2; i += 256) p[i] = 0;
  }
  __syncthreads();

  // stage Q [64][64]
#pragma unroll
  for (int j = 0; j < 2; ++j) {
    int i = t + j * 256;
    int r = i >> 3, c8 = i & 7;
    *(int4*)&Qt[r][c8 * 8] =
        *(const int4*)(Qb + (size_t)(b * S_ + q0 + r) * HID_ + h * DH_ +
                       c8 * 8);
  }
  // stage K [77][64]
#pragma unroll
  for (int j = 0; j < 3; ++j) {
    int i = t + j * 256;
    if (i < KV_ * 8) {
      int r = i >> 3, c8 = i & 7;
      *(int4*)&Kl[r][c8 * 8] =
          *(const int4*)(Kb + (size_t)(b * KV_ + r) * HID_ + h * DH_ + c8 * 8);
    }
  }
  // stage V transposed -> Vt[d][kv]
  for (int i = t; i < KV_ * DH_; i += 256) {
    int d = i & 63, kv = i >> 6;
    Vt[d][kv] = Vb[(size_t)(b * KV_ + kv) * HID_ + h * DH_ + d];
  }
  // stage AUK [16][64]
  if (t < AU_ * 8) {
    int r = t >> 3, c8 = t & 7;
    *(int4*)&AUKl[r][c8 * 8] =
        *(const int4*)(AKb + (size_t)(b * AU_ + r) * HID_ + h * DH_ + c8 * 8);
  }
  // stage AUV transposed -> AUVt[d][au]
  for (int i = t; i < AU_ * DH_; i += 256) {
    int d = i & 63, a = i >> 6;
    AUVt[d][a] = AVb[(size_t)(b * AU_ + a) * HID_ + h * DH_ + d];
  }
  __syncthreads();

  // QK^T (64x80) and AU scores (64x16)
  f32x4 z4 = {0.f, 0.f, 0.f, 0.f};
  f32x4 accS[5], accA = z4;
#pragma unroll
  for (int c = 0; c < 5; ++c) accS[c] = z4;
#pragma unroll
  for (int ks = 0; ks < 64; ks += 32) {
    bf16x8 aq = *(const bf16x8*)&Qt[rw + l15][ks + lg * 8];
#pragma unroll
    for (int c = 0; c < 5; ++c) {
      bf16x8 bk = *(const bf16x8*)&Kl[c * 16 + l15][ks + lg * 8];
      accS[c] = __builtin_amdgcn_mfma_f32_16x16x32_bf16(aq, bk, accS[c], 0, 0, 0);
    }
    bf16x8 ba = *(const bf16x8*)&AUKl[l15][ks + lg * 8];
    accA = __builtin_amdgcn_mfma_f32_16x16x32_bf16(aq, ba, accA, 0, 0, 0);
  }

  const float invT = 1.f / (fabsf(temp[0]) + 1e-6f);
#pragma unroll
  for (int j = 0; j < 4; ++j) {
    float v[5];
    float m = -1e30f;
#pragma unroll
    for (int c = 0; c < 5; ++c) {
      int col = c * 16 + l15;
      v[c] = (col < KV_) ? accS[c][j] * SCALE_ : -1e30f;
      m = fmaxf(m, v[c]);
    }
#pragma unroll
    for (int off = 1; off < 16; off <<= 1) m = fmaxf(m, __shfl_xor(m, off));
    float p[5];
    float s = 0.f;
#pragma unroll
    for (int c = 0; c < 5; ++c) {
      p[c] = (v[c] > -1e29f) ? __expf(v[c] - m) : 0.f;
      s += p[c];
    }
#pragma unroll
    for (int off = 1; off < 16; off <<= 1) s += __shfl_xor(s, off);
    float inv = 1.f / s;
    int r = rw + lg * 4 + j;
#pragma unroll
    for (int c = 0; c < 5; ++c) Pl[r][c * 16 + l15] = bfc(p[c] * inv);
    // AU mask
    float as = accA[j] * SCALE_ * invT;
    float sg = 1.f / (1.f + __expf(-as));
    float mv = sg * prior[q0 + r] * 0.9f + 0.1f;
    Ml[r][l15] = bfc(mv);
  }
  __syncthreads();

  // PV (K=96 incl. zero pad) and mask @ AUV (K=32 incl. zero pad)
  f32x4 accO[4], accAO[4];
#pragma unroll
  for (int c = 0; c < 4; ++c) {
    accO[c] = z4;
    accAO[c] = z4;
  }
#pragma unroll
  for (int kk = 0; kk < 96; kk += 32) {
    bf16x8 ap = *(const bf16x8*)&Pl[rw + l15][kk + lg * 8];
#pragma unroll
    for (int c = 0; c < 4; ++c) {
      bf16x8 bv = *(const bf16x8*)&Vt[c * 16 + l15][kk + lg * 8];
      accO[c] = __builtin_amdgcn_mfma_f32_16x16x32_bf16(ap, bv, accO[c], 0, 0, 0);
    }
  }
  {
    bf16x8 am = *(const bf16x8*)&Ml[rw + l15][lg * 8];
#pragma unroll
    for (int c = 0; c < 4; ++c) {
      bf16x8 bv = *(const bf16x8*)&AUVt[c * 16 + l15][lg * 8];
      accAO[c] =
          __builtin_amdgcn_mfma_f32_16x16x32_bf16(am, bv, accAO[c], 0, 0, 0);
    }
  }
  const float g = gate[0];  // AU_SCALE = 1
#pragma unroll
  for (int c = 0; c < 4; ++c)
#pragma unroll
    for (int j = 0; j < 4; ++j) {
      int r = rw + lg * 4 + j;
      float val = accO[c][j] + g * accAO[c][j];
      Ob[(size_t)(b * S_ + q0 + r) * HID_ + h * DH_ + c * 16 + l15] = bfc(val);
    }
}

// ---------------------------------------------------------------- launcher
extern "C" void kernel_launch(void* const* d_in, const int* in_sizes, int n_in,
                              void* d_out, int out_size, void* d_ws,
                              size_t ws_size, hipStream_t stream) {
  const float* hs = (const float*)d_in[0];
  const float* enc = (const float*)d_in[1];
  const float* au = (const float*)d_in[2];
  const float* Wq = (const float*)d_in[3];
  const float* Wk = (const float*)d_in[4];
  const float* Wv = (const float*)d_in[5];
  const float* Wauk = (const float*)d_in[6];
  const float* Wauv = (const float*)d_in[7];
  const float* Wout = (const float*)d_in[8];
  const float* bout = (const float*)d_in[9];
  const float* temp = (const float*)d_in[10];
  const float* gate = (const float*)d_in[11];
  float* out = (float*)d_out;
  char* ws = (char*)d_ws;

  const size_t szK = (size_t)B_ * KV_ * HID_ * 2;   // 788480
  const size_t szAU = (size_t)B_ * AU_ * HID_ * 2;  // 163840
  const size_t szW640 = (size_t)HID_ * HID_ * 2;    // 819200
  const size_t szW768 = (size_t)HID_ * CROSS_ * 2;  // 983040

  size_t off = 0;
  float* prior = (float*)(ws + off);  off += 16384;
  short* Kbf = (short*)(ws + off);    off += szK;
  short* Vbf = (short*)(ws + off);    off += szK;
  short* AUKbf = (short*)(ws + off);  off += szAU;
  short* AUVbf = (short*)(ws + off);  off += szAU;
  short* Wqt = (short*)(ws + off);    off += szW640;
  short* Wkt = (short*)(ws + off);    off += szW768;
  short* Wvt = (short*)(ws + off);    off += szW768;
  short* Waukt = (short*)(ws + off);  off += szW768;
  short* Wauvt = (short*)(ws + off);  off += szW768;
  short* Woutt = (short*)(ws + off);  off += szW640;
  short* Qbf = (short*)(ws + off);    // 41.94 MB; total ws ~49.5 MB
  short* Abf = Qbf;                   // ALIAS: attn overwrites Q in place

  prior_k<<<16, 256, 0, stream>>>(prior);
  wprep_k<<<dim3(10, 12, 6), 256, 0, stream>>>(Wq, Wk, Wv, Wauk, Wauv, Wout,
                                               Wqt, Wkt, Wvt, Waukt, Wauvt,
                                               Woutt);
  proj4_k<<<dim3(5, 5, 4), 256, 0, stream>>>(enc, au, Wkt, Wvt, Waukt, Wauvt,
                                             Kbf, Vbf, AUKbf, AUVbf);
  gemm_q_k<<<dim3(256, 5), 256, 0, stream>>>(hs, Wqt, Qbf, B_ * S_, HID_,
                                             HID_);
  attn_k<<<dim3(64, HEADS_, B_), 256, 0, stream>>>(Qbf, Kbf, Vbf, AUKbf, AUVbf,
                                                   prior, Abf, temp, gate);
  gemm_out_k<<<dim3(256, 5), 256, 0, stream>>>(Abf, Woutt, out, bout, hs,
                                               B_ * S_, HID_, HID_);
}

// Round 5
// 279.265 us; speedup vs baseline: 1.1833x; 1.1303x over previous
//
#include <hip/hip_runtime.h>
#include <hip/hip_bf16.h>

#define B_ 8
#define S_ 4096
#define HID_ 640
#define KV_ 77
#define AU_ 16
#define CROSS_ 768
#define HEADS_ 10
#define DH_ 64
#define SCALE_ 0.125f

using f32x4 = __attribute__((ext_vector_type(4))) float;
using bf16x8 = __attribute__((ext_vector_type(8))) short;

__device__ __forceinline__ short bfc(float f) {
  __hip_bfloat16 h = __float2bfloat16(f);
  return __builtin_bit_cast(short, h);
}

__device__ __forceinline__ void gload16(const void* g, void* lds) {
  __builtin_amdgcn_global_load_lds(
      (const __attribute__((address_space(1))) void*)g,
      (__attribute__((address_space(3))) void*)lds, 16, 0, 0);
}

// ---------------------------------------------------------------- prior table
__global__ __launch_bounds__(256) void prior_k(float* prior) {
  int i = blockIdx.x * 256 + threadIdx.x;
  if (i < S_) {
    int yy = i >> 6, xx = i & 63;
    float lx = -1.f + 2.f * (float)xx / 63.f;
    float ly = -1.f + 2.f * (float)yy / 63.f;
    prior[i] = __expf(-(lx * lx + ly * ly) * (1.0f / 0.605f));
  }
}

// ---------------------------------------------------------------- f32 -> bf16
__global__ __launch_bounds__(256) void cvt_k(const float* in, short* out,
                                             int n8) {
  int i = blockIdx.x * 256 + threadIdx.x;
  if (i >= n8) return;
  const float4 a = *(const float4*)(in + (size_t)i * 8);
  const float4 b = *(const float4*)(in + (size_t)i * 8 + 4);
  bf16x8 v;
  v[0] = bfc(a.x); v[1] = bfc(a.y); v[2] = bfc(a.z); v[3] = bfc(a.w);
  v[4] = bfc(b.x); v[5] = bfc(b.y); v[6] = bfc(b.z); v[7] = bfc(b.w);
  *(bf16x8*)(out + (size_t)i * 8) = v;
}

// ------------------------------------------------- weight transpose + convert
// W [K][640] f32 row-major  ->  Wt [640][K] bf16 row-major.
__global__ __launch_bounds__(256) void wprep_k(
    const float* Wq, const float* Wk, const float* Wv, const float* Wauk,
    const float* Wauv, const float* Wout, short* Wqt, short* Wkt, short* Wvt,
    short* Waukt, short* Wauvt, short* Woutt) {
  const float* W;
  short* Wt;
  int K;
  switch (blockIdx.z) {
    case 0: W = Wq;   Wt = Wqt;   K = 640; break;
    case 1: W = Wk;   Wt = Wkt;   K = 768; break;
    case 2: W = Wv;   Wt = Wvt;   K = 768; break;
    case 3: W = Wauk; Wt = Waukt; K = 768; break;
    case 4: W = Wauv; Wt = Wauvt; K = 768; break;
    default: W = Wout; Wt = Woutt; K = 640; break;
  }
  int kt = blockIdx.y * 64, nt = blockIdx.x * 64;
  if (kt >= K) return;
  __shared__ short Tl[64][72];
  const int t = threadIdx.x;
#pragma unroll
  for (int j = 0; j < 16; ++j) {
    int i = t + j * 256;
    int r = i >> 6, c = i & 63;
    Tl[c][r] = bfc(W[(size_t)(kt + r) * 640 + nt + c]);
  }
  __syncthreads();
#pragma unroll
  for (int j = 0; j < 2; ++j) {
    int i = t + j * 256;
    int nl = i >> 3, c = i & 7;
    *(int4*)&Wt[(size_t)(nt + nl) * K + kt + c * 8] = *(int4*)&Tl[nl][c * 8];
  }
}

// ------------------------------------------------- big GEMM (256x128 tile)
// C[m0+256, n0+128] = A[M,K]bf16 @ Bt[N,K]bf16^T. M,N exact multiples.
// global_load_lds staging, linear LDS + XOR swizzle (byte ^= (row&7)<<4),
// pre-swizzled global source (rule #21: source and read use same involution).
template <bool EPI>
__device__ __forceinline__ void gemm256(const short* Abf, const short* Bt,
                                        void* Cout, const float* bias,
                                        const float* resid, int K, int N,
                                        int m0, int n0) {
  __shared__ short Al[256 * 64];
  __shared__ short Bl[128 * 64];
  const int t = threadIdx.x;
  const int lane = t & 63;
  const int wave = t >> 6;  // 0..7
  const int l15 = lane & 15, lg = lane >> 4;
  const int wr = (wave >> 1) * 64;  // 0,64,128,192
  const int wc = (wave & 1) * 64;   // 0,64

  f32x4 z4 = {0.f, 0.f, 0.f, 0.f};
  f32x4 acc[4][4];
#pragma unroll
  for (int i = 0; i < 4; ++i)
#pragma unroll
    for (int j = 0; j < 4; ++j) acc[i][j] = z4;

  for (int k0 = 0; k0 < K; k0 += 64) {
    // A stage: 2048 chunks of 16B; wave w -> chunks [w*256, w*256+256)
#pragma unroll
    for (int i = 0; i < 4; ++i) {
      int chunk = wave * 256 + i * 64 + lane;
      int r = chunk >> 3, s = chunk & 7;
      const short* src =
          Abf + (size_t)(m0 + r) * K + k0 + ((s ^ (r & 7)) << 3);
      gload16(src, Al + (size_t)(wave * 256 + i * 64) * 8);
    }
    // B stage: 1024 chunks; wave w -> chunks [w*128, w*128+128)
#pragma unroll
    for (int i = 0; i < 2; ++i) {
      int chunk = wave * 128 + i * 64 + lane;
      int r = chunk >> 3, s = chunk & 7;
      const short* src =
          Bt + (size_t)(n0 + r) * K + k0 + ((s ^ (r & 7)) << 3);
      gload16(src, Bl + (size_t)(wave * 128 + i * 64) * 8);
    }
    __syncthreads();
#pragma unroll
    for (int ks = 0; ks < 2; ++ks) {
      bf16x8 af[4], bfr[4];
#pragma unroll
      for (int mi = 0; mi < 4; ++mi) {
        int row = wr + mi * 16 + l15;
        int boff = (ks * 64 + lg * 16) ^ ((row & 7) << 4);
        af[mi] = *(const bf16x8*)((const char*)(Al + row * 64) + boff);
      }
#pragma unroll
      for (int ni = 0; ni < 4; ++ni) {
        int row = wc + ni * 16 + l15;
        int boff = (ks * 64 + lg * 16) ^ ((row & 7) << 4);
        bfr[ni] = *(const bf16x8*)((const char*)(Bl + row * 64) + boff);
      }
#pragma unroll
      for (int mi = 0; mi < 4; ++mi)
#pragma unroll
        for (int ni = 0; ni < 4; ++ni)
          acc[mi][ni] = __builtin_amdgcn_mfma_f32_16x16x32_bf16(
              af[mi], bfr[ni], acc[mi][ni], 0, 0, 0);
    }
    __syncthreads();
  }
  // epilogue
#pragma unroll
  for (int mi = 0; mi < 4; ++mi) {
#pragma unroll
    for (int j = 0; j < 4; ++j) {
      int row = m0 + wr + mi * 16 + lg * 4 + j;
#pragma unroll
      for (int ni = 0; ni < 4; ++ni) {
        int col = n0 + wc + ni * 16 + l15;
        size_t idx = (size_t)row * N + col;
        float val = acc[mi][ni][j];
        if (EPI) {
          ((float*)Cout)[idx] = val + bias[col] + resid[idx];
        } else {
          ((short*)Cout)[idx] = bfc(val);
        }
      }
    }
  }
}

__global__ __launch_bounds__(512, 4) void gemm_q_k(const short* A,
                                                   const short* Bt, short* C) {
  gemm256<false>(A, Bt, C, nullptr, nullptr, HID_, HID_, blockIdx.x * 256,
                 blockIdx.y * 128);
}

__global__ __launch_bounds__(512, 4) void gemm_out_k(const short* A,
                                                     const short* Bt, float* C,
                                                     const float* bias,
                                                     const float* resid) {
  gemm256<true>(A, Bt, C, bias, resid, HID_, HID_, blockIdx.x * 256,
                blockIdx.y * 128);
}

// ---------------------------------------------------------------- small GEMM
// (proj4 only) C[m0+128,n0+128] = A[M,K]f32 @ Bt[N,K]bf16^T -> bf16.
__device__ __forceinline__ void gemm_small(const float* A32, const short* Bt,
                                           short* Cout, int M, int K, int N,
                                           int m0, int n0) {
  __shared__ short Al[128][72];
  __shared__ short Bl[128][72];
  const int t = threadIdx.x;
  const int lane = t & 63;
  const int wave = t >> 6;
  const int l15 = lane & 15, lg = lane >> 4;
  const int wr = (wave >> 1) * 64, wc = (wave & 1) * 64;

  f32x4 z4 = {0.f, 0.f, 0.f, 0.f};
  f32x4 acc[4][4];
#pragma unroll
  for (int i = 0; i < 4; ++i)
#pragma unroll
    for (int j = 0; j < 4; ++j) acc[i][j] = z4;

  for (int k0 = 0; k0 < K; k0 += 64) {
#pragma unroll
    for (int j = 0; j < 8; ++j) {
      int i = t + j * 256;
      int r = i >> 4, q = i & 15;
      int row = m0 + r;
      float4 v = {0.f, 0.f, 0.f, 0.f};
      if (row < M) v = *(const float4*)(A32 + (size_t)row * K + k0 + q * 4);
      short4 s;
      s.x = bfc(v.x);
      s.y = bfc(v.y);
      s.z = bfc(v.z);
      s.w = bfc(v.w);
      *(short4*)&Al[r][q * 4] = s;
    }
#pragma unroll
    for (int j = 0; j < 4; ++j) {
      int i = t + j * 256;
      int row = i >> 3, c = i & 7;
      *(int4*)&Bl[row][c * 8] =
          *(const int4*)(Bt + (size_t)(n0 + row) * K + k0 + c * 8);
    }
    __syncthreads();
#pragma unroll
    for (int ks = 0; ks < 64; ks += 32) {
      bf16x8 af[4], bfr[4];
#pragma unroll
      for (int mi = 0; mi < 4; ++mi)
        af[mi] = *(const bf16x8*)&Al[wr + mi * 16 + l15][ks + lg * 8];
#pragma unroll
      for (int ni = 0; ni < 4; ++ni)
        bfr[ni] = *(const bf16x8*)&Bl[wc + ni * 16 + l15][ks + lg * 8];
#pragma unroll
      for (int mi = 0; mi < 4; ++mi)
#pragma unroll
        for (int ni = 0; ni < 4; ++ni)
          acc[mi][ni] = __builtin_amdgcn_mfma_f32_16x16x32_bf16(
              af[mi], bfr[ni], acc[mi][ni], 0, 0, 0);
    }
    __syncthreads();
  }
#pragma unroll
  for (int mi = 0; mi < 4; ++mi) {
#pragma unroll
    for (int j = 0; j < 4; ++j) {
      int row = m0 + wr + mi * 16 + lg * 4 + j;
      if (row >= M) continue;
#pragma unroll
      for (int ni = 0; ni < 4; ++ni) {
        int col = n0 + wc + ni * 16 + l15;
        Cout[(size_t)row * N + col] = bfc(acc[mi][ni][j]);
      }
    }
  }
}

__global__ __launch_bounds__(256) void proj4_k(const float* enc,
                                               const float* au,
                                               const short* Wkt,
                                               const short* Wvt,
                                               const short* Waukt,
                                               const short* Wauvt, short* Kb,
                                               short* Vb, short* AKb,
                                               short* AVb) {
  int z = blockIdx.z;
  const float* A = (z < 2) ? enc : au;
  const short* Bt = (z == 0) ? Wkt : (z == 1) ? Wvt : (z == 2) ? Waukt : Wauvt;
  short* O = (z == 0) ? Kb : (z == 1) ? Vb : (z == 2) ? AKb : AVb;
  int M = (z < 2) ? (B_ * KV_) : (B_ * AU_);
  if ((int)blockIdx.x * 128 >= M) return;
  gemm_small(A, Bt, O, M, CROSS_, HID_, blockIdx.x * 128, blockIdx.y * 128);
}

// ---------------------------------------------------------------- attention
// NOTE: Ob may alias Qb (in-place) — block (q0,h,b) reads exactly the Q region
// it later writes; reads complete before the staging barrier. Race-free.
__global__ __launch_bounds__(256) void attn_k(const short* Qb, const short* Kb,
                                              const short* Vb, const short* AKb,
                                              const short* AVb,
                                              const float* prior, short* Ob,
                                              const float* temp,
                                              const float* gate) {
  __shared__ short Qt[64][72];
  __shared__ short Kl[80][72];
  __shared__ short Vt[64][104];
  __shared__ short Pl[64][104];
  __shared__ short AUKl[16][72];
  __shared__ short AUVt[64][40];
  __shared__ short Ml[64][40];

  const int t = threadIdx.x;
  const int lane = t & 63, wave = t >> 6;
  const int l15 = lane & 15, lg = lane >> 4;
  const int q0 = blockIdx.x * 64;
  const int h = blockIdx.y;
  const int b = blockIdx.z;
  const int rw = wave * 16;

  {
    int* p = (int*)&Vt[0][0];
    for (int i = t; i < 64 * 104 / 2; i += 256) p[i] = 0;
    p = (int*)&Pl[0][0];
    for (int i = t; i < 64 * 104 / 2; i += 256) p[i] = 0;
    p = (int*)&AUVt[0][0];
    for (int i = t; i < 64 * 40 / 2; i += 256) p[i] = 0;
    p = (int*)&Ml[0][0];
    for (int i = t; i < 64 * 40 / 2; i += 256) p[i] = 0;
    p = (int*)&Kl[77][0];
    for (int i = t; i < 3 * 72 / 2; i += 256) p[i] = 0;
  }
  __syncthreads();

#pragma unroll
  for (int j = 0; j < 2; ++j) {
    int i = t + j * 256;
    int r = i >> 3, c8 = i & 7;
    *(int4*)&Qt[r][c8 * 8] =
        *(const int4*)(Qb + (size_t)(b * S_ + q0 + r) * HID_ + h * DH_ +
                       c8 * 8);
  }
#pragma unroll
  for (int j = 0; j < 3; ++j) {
    int i = t + j * 256;
    if (i < KV_ * 8) {
      int r = i >> 3, c8 = i & 7;
      *(int4*)&Kl[r][c8 * 8] =
          *(const int4*)(Kb + (size_t)(b * KV_ + r) * HID_ + h * DH_ + c8 * 8);
    }
  }
  for (int i = t; i < KV_ * DH_; i += 256) {
    int d = i & 63, kv = i >> 6;
    Vt[d][kv] = Vb[(size_t)(b * KV_ + kv) * HID_ + h * DH_ + d];
  }
  if (t < AU_ * 8) {
    int r = t >> 3, c8 = t & 7;
    *(int4*)&AUKl[r][c8 * 8] =
        *(const int4*)(AKb + (size_t)(b * AU_ + r) * HID_ + h * DH_ + c8 * 8);
  }
  for (int i = t; i < AU_ * DH_; i += 256) {
    int d = i & 63, a = i >> 6;
    AUVt[d][a] = AVb[(size_t)(b * AU_ + a) * HID_ + h * DH_ + d];
  }
  __syncthreads();

  f32x4 z4 = {0.f, 0.f, 0.f, 0.f};
  f32x4 accS[5], accA = z4;
#pragma unroll
  for (int c = 0; c < 5; ++c) accS[c] = z4;
#pragma unroll
  for (int ks = 0; ks < 64; ks += 32) {
    bf16x8 aq = *(const bf16x8*)&Qt[rw + l15][ks + lg * 8];
#pragma unroll
    for (int c = 0; c < 5; ++c) {
      bf16x8 bk = *(const bf16x8*)&Kl[c * 16 + l15][ks + lg * 8];
      accS[c] = __builtin_amdgcn_mfma_f32_16x16x32_bf16(aq, bk, accS[c], 0, 0, 0);
    }
    bf16x8 ba = *(const bf16x8*)&AUKl[l15][ks + lg * 8];
    accA = __builtin_amdgcn_mfma_f32_16x16x32_bf16(aq, ba, accA, 0, 0, 0);
  }

  const float invT = 1.f / (fabsf(temp[0]) + 1e-6f);
#pragma unroll
  for (int j = 0; j < 4; ++j) {
    float v[5];
    float m = -1e30f;
#pragma unroll
    for (int c = 0; c < 5; ++c) {
      int col = c * 16 + l15;
      v[c] = (col < KV_) ? accS[c][j] * SCALE_ : -1e30f;
      m = fmaxf(m, v[c]);
    }
#pragma unroll
    for (int off = 1; off < 16; off <<= 1) m = fmaxf(m, __shfl_xor(m, off));
    float p[5];
    float s = 0.f;
#pragma unroll
    for (int c = 0; c < 5; ++c) {
      p[c] = (v[c] > -1e29f) ? __expf(v[c] - m) : 0.f;
      s += p[c];
    }
#pragma unroll
    for (int off = 1; off < 16; off <<= 1) s += __shfl_xor(s, off);
    float inv = 1.f / s;
    int r = rw + lg * 4 + j;
#pragma unroll
    for (int c = 0; c < 5; ++c) Pl[r][c * 16 + l15] = bfc(p[c] * inv);
    float as = accA[j] * SCALE_ * invT;
    float sg = 1.f / (1.f + __expf(-as));
    float mv = sg * prior[q0 + r] * 0.9f + 0.1f;
    Ml[r][l15] = bfc(mv);
  }
  __syncthreads();

  f32x4 accO[4], accAO[4];
#pragma unroll
  for (int c = 0; c < 4; ++c) {
    accO[c] = z4;
    accAO[c] = z4;
  }
#pragma unroll
  for (int kk = 0; kk < 96; kk += 32) {
    bf16x8 ap = *(const bf16x8*)&Pl[rw + l15][kk + lg * 8];
#pragma unroll
    for (int c = 0; c < 4; ++c) {
      bf16x8 bv = *(const bf16x8*)&Vt[c * 16 + l15][kk + lg * 8];
      accO[c] = __builtin_amdgcn_mfma_f32_16x16x32_bf16(ap, bv, accO[c], 0, 0, 0);
    }
  }
  {
    bf16x8 am = *(const bf16x8*)&Ml[rw + l15][lg * 8];
#pragma unroll
    for (int c = 0; c < 4; ++c) {
      bf16x8 bv = *(const bf16x8*)&AUVt[c * 16 + l15][lg * 8];
      accAO[c] =
          __builtin_amdgcn_mfma_f32_16x16x32_bf16(am, bv, accAO[c], 0, 0, 0);
    }
  }
  const float g = gate[0];  // AU_SCALE = 1
#pragma unroll
  for (int c = 0; c < 4; ++c)
#pragma unroll
    for (int j = 0; j < 4; ++j) {
      int r = rw + lg * 4 + j;
      float val = accO[c][j] + g * accAO[c][j];
      Ob[(size_t)(b * S_ + q0 + r) * HID_ + h * DH_ + c * 16 + l15] = bfc(val);
    }
}

// ---------------------------------------------------------------- launcher
extern "C" void kernel_launch(void* const* d_in, const int* in_sizes, int n_in,
                              void* d_out, int out_size, void* d_ws,
                              size_t ws_size, hipStream_t stream) {
  const float* hs = (const float*)d_in[0];
  const float* enc = (const float*)d_in[1];
  const float* au = (const float*)d_in[2];
  const float* Wq = (const float*)d_in[3];
  const float* Wk = (const float*)d_in[4];
  const float* Wv = (const float*)d_in[5];
  const float* Wauk = (const float*)d_in[6];
  const float* Wauv = (const float*)d_in[7];
  const float* Wout = (const float*)d_in[8];
  const float* bout = (const float*)d_in[9];
  const float* temp = (const float*)d_in[10];
  const float* gate = (const float*)d_in[11];
  float* out = (float*)d_out;
  char* ws = (char*)d_ws;

  const size_t szK = (size_t)B_ * KV_ * HID_ * 2;   // 788480
  const size_t szAU = (size_t)B_ * AU_ * HID_ * 2;  // 163840
  const size_t szW640 = (size_t)HID_ * HID_ * 2;    // 819200
  const size_t szW768 = (size_t)HID_ * CROSS_ * 2;  // 983040

  size_t off = 0;
  float* prior = (float*)(ws + off);  off += 16384;
  short* Kbf = (short*)(ws + off);    off += szK;
  short* Vbf = (short*)(ws + off);    off += szK;
  short* AUKbf = (short*)(ws + off);  off += szAU;
  short* AUVbf = (short*)(ws + off);  off += szAU;
  short* Wqt = (short*)(ws + off);    off += szW640;
  short* Wkt = (short*)(ws + off);    off += szW768;
  short* Wvt = (short*)(ws + off);    off += szW768;
  short* Waukt = (short*)(ws + off);  off += szW768;
  short* Wauvt = (short*)(ws + off);  off += szW768;
  short* Woutt = (short*)(ws + off);  off += szW640;
  short* Qbf = (short*)(ws + off);    // 41.94 MB; total ws ~49.5 MB
  short* Abf = Qbf;                   // ALIAS: attn overwrites Q in place
  // hs-bf16 lives in d_out (83.9 MB f32 buffer; first 41.9 MB used as
  // scratch, dead before gemm_out_k writes the real output). Deterministic:
  // fully rewritten every call.
  short* hsb = (short*)d_out;

  prior_k<<<16, 256, 0, stream>>>(prior);
  wprep_k<<<dim3(10, 12, 6), 256, 0, stream>>>(Wq, Wk, Wv, Wauk, Wauv, Wout,
                                               Wqt, Wkt, Wvt, Waukt, Wauvt,
                                               Woutt);
  cvt_k<<<10240, 256, 0, stream>>>(hs, hsb, (B_ * S_ * HID_) / 8);
  proj4_k<<<dim3(5, 5, 4), 256, 0, stream>>>(enc, au, Wkt, Wvt, Waukt, Wauvt,
                                             Kbf, Vbf, AUKbf, AUVbf);
  gemm_q_k<<<dim3(128, 5), 512, 0, stream>>>(hsb, Wqt, Qbf);
  attn_k<<<dim3(64, HEADS_, B_), 256, 0, stream>>>(Qbf, Kbf, Vbf, AUKbf, AUVbf,
                                                   prior, Abf, temp, gate);
  gemm_out_k<<<dim3(128, 5), 512, 0, stream>>>(Abf, Woutt, out, bout, hs);
}

// Round 6
// 237.988 us; speedup vs baseline: 1.3885x; 1.1734x over previous
//
#include <hip/hip_runtime.h>
#include <hip/hip_bf16.h>

#define B_ 8
#define S_ 4096
#define HID_ 640
#define KV_ 77
#define AU_ 16
#define CROSS_ 768
#define HEADS_ 10
#define DH_ 64
#define SCALE_ 0.125f

using f32x4 = __attribute__((ext_vector_type(4))) float;
using bf16x8 = __attribute__((ext_vector_type(8))) short;

__device__ __forceinline__ short bfc(float f) {
  __hip_bfloat16 h = __float2bfloat16(f);
  return __builtin_bit_cast(short, h);
}

__device__ __forceinline__ void gload16(const void* g, void* lds) {
  __builtin_amdgcn_global_load_lds(
      (const __attribute__((address_space(1))) void*)g,
      (__attribute__((address_space(3))) void*)lds, 16, 0, 0);
}

// ---------------------------------------------------------------- prior table
__global__ __launch_bounds__(256) void prior_k(float* prior) {
  int i = blockIdx.x * 256 + threadIdx.x;
  if (i < S_) {
    int yy = i >> 6, xx = i & 63;
    float lx = -1.f + 2.f * (float)xx / 63.f;
    float ly = -1.f + 2.f * (float)yy / 63.f;
    prior[i] = __expf(-(lx * lx + ly * ly) * (1.0f / 0.605f));
  }
}

// ---------------------------------------------------------------- f32 -> bf16
__global__ __launch_bounds__(256) void cvt_k(const float* in, short* out,
                                             int n8) {
  int i = blockIdx.x * 256 + threadIdx.x;
  if (i >= n8) return;
  const float4 a = *(const float4*)(in + (size_t)i * 8);
  const float4 b = *(const float4*)(in + (size_t)i * 8 + 4);
  bf16x8 v;
  v[0] = bfc(a.x); v[1] = bfc(a.y); v[2] = bfc(a.z); v[3] = bfc(a.w);
  v[4] = bfc(b.x); v[5] = bfc(b.y); v[6] = bfc(b.z); v[7] = bfc(b.w);
  *(bf16x8*)(out + (size_t)i * 8) = v;
}

// ------------------------------------------------- weight transpose + convert
// W [K][640] f32 row-major  ->  Wt [640][K] bf16 row-major.
__global__ __launch_bounds__(256) void wprep_k(
    const float* Wq, const float* Wk, const float* Wv, const float* Wauk,
    const float* Wauv, const float* Wout, short* Wqt, short* Wkt, short* Wvt,
    short* Waukt, short* Wauvt, short* Woutt) {
  const float* W;
  short* Wt;
  int K;
  switch (blockIdx.z) {
    case 0: W = Wq;   Wt = Wqt;   K = 640; break;
    case 1: W = Wk;   Wt = Wkt;   K = 768; break;
    case 2: W = Wv;   Wt = Wvt;   K = 768; break;
    case 3: W = Wauk; Wt = Waukt; K = 768; break;
    case 4: W = Wauv; Wt = Wauvt; K = 768; break;
    default: W = Wout; Wt = Woutt; K = 640; break;
  }
  int kt = blockIdx.y * 64, nt = blockIdx.x * 64;
  if (kt >= K) return;
  __shared__ short Tl[64][72];
  const int t = threadIdx.x;
#pragma unroll
  for (int j = 0; j < 16; ++j) {
    int i = t + j * 256;
    int r = i >> 6, c = i & 63;
    Tl[c][r] = bfc(W[(size_t)(kt + r) * 640 + nt + c]);
  }
  __syncthreads();
#pragma unroll
  for (int j = 0; j < 2; ++j) {
    int i = t + j * 256;
    int nl = i >> 3, c = i & 7;
    *(int4*)&Wt[(size_t)(nt + nl) * K + kt + c * 8] = *(int4*)&Tl[nl][c * 8];
  }
}

// ------------------------------------------------- big GEMM (256x128 tile)
template <bool EPI>
__device__ __forceinline__ void gemm256(const short* Abf, const short* Bt,
                                        void* Cout, const float* bias,
                                        const float* resid, int K, int N,
                                        int m0, int n0) {
  __shared__ short Al[256 * 64];
  __shared__ short Bl[128 * 64];
  const int t = threadIdx.x;
  const int lane = t & 63;
  const int wave = t >> 6;  // 0..7
  const int l15 = lane & 15, lg = lane >> 4;
  const int wr = (wave >> 1) * 64;
  const int wc = (wave & 1) * 64;

  f32x4 z4 = {0.f, 0.f, 0.f, 0.f};
  f32x4 acc[4][4];
#pragma unroll
  for (int i = 0; i < 4; ++i)
#pragma unroll
    for (int j = 0; j < 4; ++j) acc[i][j] = z4;

  for (int k0 = 0; k0 < K; k0 += 64) {
#pragma unroll
    for (int i = 0; i < 4; ++i) {
      int chunk = wave * 256 + i * 64 + lane;
      int r = chunk >> 3, s = chunk & 7;
      const short* src =
          Abf + (size_t)(m0 + r) * K + k0 + ((s ^ (r & 7)) << 3);
      gload16(src, Al + (size_t)(wave * 256 + i * 64) * 8);
    }
#pragma unroll
    for (int i = 0; i < 2; ++i) {
      int chunk = wave * 128 + i * 64 + lane;
      int r = chunk >> 3, s = chunk & 7;
      const short* src =
          Bt + (size_t)(n0 + r) * K + k0 + ((s ^ (r & 7)) << 3);
      gload16(src, Bl + (size_t)(wave * 128 + i * 64) * 8);
    }
    __syncthreads();
#pragma unroll
    for (int ks = 0; ks < 2; ++ks) {
      bf16x8 af[4], bfr[4];
#pragma unroll
      for (int mi = 0; mi < 4; ++mi) {
        int row = wr + mi * 16 + l15;
        int boff = (ks * 64 + lg * 16) ^ ((row & 7) << 4);
        af[mi] = *(const bf16x8*)((const char*)(Al + row * 64) + boff);
      }
#pragma unroll
      for (int ni = 0; ni < 4; ++ni) {
        int row = wc + ni * 16 + l15;
        int boff = (ks * 64 + lg * 16) ^ ((row & 7) << 4);
        bfr[ni] = *(const bf16x8*)((const char*)(Bl + row * 64) + boff);
      }
#pragma unroll
      for (int mi = 0; mi < 4; ++mi)
#pragma unroll
        for (int ni = 0; ni < 4; ++ni)
          acc[mi][ni] = __builtin_amdgcn_mfma_f32_16x16x32_bf16(
              af[mi], bfr[ni], acc[mi][ni], 0, 0, 0);
    }
    __syncthreads();
  }
#pragma unroll
  for (int mi = 0; mi < 4; ++mi) {
#pragma unroll
    for (int j = 0; j < 4; ++j) {
      int row = m0 + wr + mi * 16 + lg * 4 + j;
#pragma unroll
      for (int ni = 0; ni < 4; ++ni) {
        int col = n0 + wc + ni * 16 + l15;
        size_t idx = (size_t)row * N + col;
        float val = acc[mi][ni][j];
        if (EPI) {
          ((float*)Cout)[idx] = val + bias[col] + resid[idx];
        } else {
          ((short*)Cout)[idx] = bfc(val);
        }
      }
    }
  }
}

__global__ __launch_bounds__(512, 4) void gemm_q_k(const short* A,
                                                   const short* Bt, short* C) {
  gemm256<false>(A, Bt, C, nullptr, nullptr, HID_, HID_, blockIdx.x * 256,
                 blockIdx.y * 128);
}

__global__ __launch_bounds__(512, 4) void gemm_out_k(const short* A,
                                                     const short* Bt, float* C,
                                                     const float* bias,
                                                     const float* resid) {
  gemm256<true>(A, Bt, C, bias, resid, HID_, HID_, blockIdx.x * 256,
                blockIdx.y * 128);
}

// ---------------------------------------------------------------- small GEMM
__device__ __forceinline__ void gemm_small(const float* A32, const short* Bt,
                                           short* Cout, int M, int K, int N,
                                           int m0, int n0) {
  __shared__ short Al[128][72];
  __shared__ short Bl[128][72];
  const int t = threadIdx.x;
  const int lane = t & 63;
  const int wave = t >> 6;
  const int l15 = lane & 15, lg = lane >> 4;
  const int wr = (wave >> 1) * 64, wc = (wave & 1) * 64;

  f32x4 z4 = {0.f, 0.f, 0.f, 0.f};
  f32x4 acc[4][4];
#pragma unroll
  for (int i = 0; i < 4; ++i)
#pragma unroll
    for (int j = 0; j < 4; ++j) acc[i][j] = z4;

  for (int k0 = 0; k0 < K; k0 += 64) {
#pragma unroll
    for (int j = 0; j < 8; ++j) {
      int i = t + j * 256;
      int r = i >> 4, q = i & 15;
      int row = m0 + r;
      float4 v = {0.f, 0.f, 0.f, 0.f};
      if (row < M) v = *(const float4*)(A32 + (size_t)row * K + k0 + q * 4);
      short4 s;
      s.x = bfc(v.x);
      s.y = bfc(v.y);
      s.z = bfc(v.z);
      s.w = bfc(v.w);
      *(short4*)&Al[r][q * 4] = s;
    }
#pragma unroll
    for (int j = 0; j < 4; ++j) {
      int i = t + j * 256;
      int row = i >> 3, c = i & 7;
      *(int4*)&Bl[row][c * 8] =
          *(const int4*)(Bt + (size_t)(n0 + row) * K + k0 + c * 8);
    }
    __syncthreads();
#pragma unroll
    for (int ks = 0; ks < 64; ks += 32) {
      bf16x8 af[4], bfr[4];
#pragma unroll
      for (int mi = 0; mi < 4; ++mi)
        af[mi] = *(const bf16x8*)&Al[wr + mi * 16 + l15][ks + lg * 8];
#pragma unroll
      for (int ni = 0; ni < 4; ++ni)
        bfr[ni] = *(const bf16x8*)&Bl[wc + ni * 16 + l15][ks + lg * 8];
#pragma unroll
      for (int mi = 0; mi < 4; ++mi)
#pragma unroll
        for (int ni = 0; ni < 4; ++ni)
          acc[mi][ni] = __builtin_amdgcn_mfma_f32_16x16x32_bf16(
              af[mi], bfr[ni], acc[mi][ni], 0, 0, 0);
    }
    __syncthreads();
  }
#pragma unroll
  for (int mi = 0; mi < 4; ++mi) {
#pragma unroll
    for (int j = 0; j < 4; ++j) {
      int row = m0 + wr + mi * 16 + lg * 4 + j;
      if (row >= M) continue;
#pragma unroll
      for (int ni = 0; ni < 4; ++ni) {
        int col = n0 + wc + ni * 16 + l15;
        Cout[(size_t)row * N + col] = bfc(acc[mi][ni][j]);
      }
    }
  }
}

__global__ __launch_bounds__(256) void proj4_k(const float* enc,
                                               const float* au,
                                               const short* Wkt,
                                               const short* Wvt,
                                               const short* Waukt,
                                               const short* Wauvt, short* Kb,
                                               short* Vb, short* AKb,
                                               short* AVb) {
  int z = blockIdx.z;
  const float* A = (z < 2) ? enc : au;
  const short* Bt = (z == 0) ? Wkt : (z == 1) ? Wvt : (z == 2) ? Waukt : Wauvt;
  short* O = (z == 0) ? Kb : (z == 1) ? Vb : (z == 2) ? AKb : AVb;
  int M = (z < 2) ? (B_ * KV_) : (B_ * AU_);
  if ((int)blockIdx.x * 128 >= M) return;
  gemm_small(A, Bt, O, M, CROSS_, HID_, blockIdx.x * 128, blockIdx.y * 128);
}

// ---------------------------------------------------------------- attention
// v2: one block per (512-row q-chunk, h, b); K/V/AU staged ONCE, 8-iter Q loop.
// Ob may alias Qb: iter qi writes rows [q0,q0+64) only after reading them;
// later iters read strictly later rows. Cross-block regions disjoint.
__global__ __launch_bounds__(256) void attn_k(const short* Qb, const short* Kb,
                                              const short* Vb, const short* AKb,
                                              const short* AVb,
                                              const float* prior, short* Ob,
                                              const float* temp,
                                              const float* gate) {
  __shared__ short Qt[64 * 64];   // linear, XOR-swizzled (gload16 dest)
  __shared__ short Kl[80][72];
  __shared__ short Vt[64][104];
  __shared__ short Pl[64][104];
  __shared__ short AUKl[16][72];
  __shared__ short AUVt[64][40];
  __shared__ short Ml[64][40];

  const int t = threadIdx.x;
  const int lane = t & 63, wave = t >> 6;
  const int l15 = lane & 15, lg = lane >> 4;
  const int qbase = blockIdx.x * 512;
  const int h = blockIdx.y;
  const int b = blockIdx.z;
  const int rw = wave * 16;
  f32x4 z4 = {0.f, 0.f, 0.f, 0.f};

  // ---- one-time zero of PAD regions only (disjoint from staged writes)
  // Vt cols 77..103
  for (int i = t; i < 64 * 27; i += 256) {
    int r = i / 27, c = i - r * 27;
    Vt[r][77 + c] = 0;
  }
  // Pl cols 80..95 (PV reads up to col 95; softmax rewrites 0..79 each iter)
  for (int i = t; i < 64 * 8; i += 256) {
    int r = i >> 3, c = i & 7;
    *(int*)&Pl[r][80 + c * 2] = 0;
  }
  // AUVt cols 16..39
  for (int i = t; i < 64 * 12; i += 256) {
    int r = i / 12, c = i - r * 12;
    *(int*)&AUVt[r][16 + c * 2] = 0;
  }
  // Ml cols 16..39
  for (int i = t; i < 64 * 12; i += 256) {
    int r = i / 12, c = i - r * 12;
    *(int*)&Ml[r][16 + c * 2] = 0;
  }
  // ---- one-time stage K [77][64] (rows 77..79 garbage-tolerated: masked)
#pragma unroll
  for (int j = 0; j < 3; ++j) {
    int i = t + j * 256;
    if (i < KV_ * 8) {
      int r = i >> 3, c8 = i & 7;
      *(int4*)&Kl[r][c8 * 8] =
          *(const int4*)(Kb + (size_t)(b * KV_ + r) * HID_ + h * DH_ + c8 * 8);
    }
  }
  // V transposed -> Vt[d][kv]
  for (int i = t; i < KV_ * DH_; i += 256) {
    int d = i & 63, kv = i >> 6;
    Vt[d][kv] = Vb[(size_t)(b * KV_ + kv) * HID_ + h * DH_ + d];
  }
  // AUK [16][64]
  if (t < AU_ * 8) {
    int r = t >> 3, c8 = t & 7;
    *(int4*)&AUKl[r][c8 * 8] =
        *(const int4*)(AKb + (size_t)(b * AU_ + r) * HID_ + h * DH_ + c8 * 8);
  }
  // AUV transposed -> AUVt[d][au]
  for (int i = t; i < AU_ * DH_; i += 256) {
    int d = i & 63, a = i >> 6;
    AUVt[d][a] = AVb[(size_t)(b * AU_ + a) * HID_ + h * DH_ + d];
  }

  const float invT = 1.f / (fabsf(temp[0]) + 1e-6f);
  const float g = gate[0];  // AU_SCALE = 1

  for (int qi = 0; qi < 8; ++qi) {
    const int q0 = qbase + qi * 64;
    // stage Q via global_load_lds, pre-swizzled source (involution s^=(r&7))
#pragma unroll
    for (int i2 = 0; i2 < 2; ++i2) {
      int chunk = wave * 128 + i2 * 64 + lane;
      int r = chunk >> 3, s = chunk & 7;
      const short* src = Qb + (size_t)(b * S_ + q0 + r) * HID_ + h * DH_ +
                         ((s ^ (r & 7)) << 3);
      gload16(src, Qt + (wave * 128 + i2 * 64) * 8);
    }
    __syncthreads();  // Q visible; also orders prev iter's Pl copy vs softmax

    // QK^T (64x80) + AU scores (64x16)
    f32x4 accS[5], accA = z4;
#pragma unroll
    for (int c = 0; c < 5; ++c) accS[c] = z4;
#pragma unroll
    for (int ks = 0; ks < 2; ++ks) {
      const char* qrow = (const char*)(Qt + (rw + l15) * 64);
      bf16x8 aq =
          *(const bf16x8*)(qrow + ((ks * 64 + lg * 16) ^ ((l15 & 7) << 4)));
#pragma unroll
      for (int c = 0; c < 5; ++c) {
        bf16x8 bk = *(const bf16x8*)&Kl[c * 16 + l15][ks * 32 + lg * 8];
        accS[c] =
            __builtin_amdgcn_mfma_f32_16x16x32_bf16(aq, bk, accS[c], 0, 0, 0);
      }
      bf16x8 ba = *(const bf16x8*)&AUKl[l15][ks * 32 + lg * 8];
      accA = __builtin_amdgcn_mfma_f32_16x16x32_bf16(aq, ba, accA, 0, 0, 0);
    }

    // softmax + AU mask (wave-local rows)
#pragma unroll
    for (int j = 0; j < 4; ++j) {
      float v[5];
      float m = -1e30f;
#pragma unroll
      for (int c = 0; c < 5; ++c) {
        int col = c * 16 + l15;
        v[c] = (col < KV_) ? accS[c][j] * SCALE_ : -1e30f;
        m = fmaxf(m, v[c]);
      }
#pragma unroll
      for (int off = 1; off < 16; off <<= 1) m = fmaxf(m, __shfl_xor(m, off));
      float p[5];
      float s = 0.f;
#pragma unroll
      for (int c = 0; c < 5; ++c) {
        p[c] = (v[c] > -1e29f) ? __expf(v[c] - m) : 0.f;
        s += p[c];
      }
#pragma unroll
      for (int off = 1; off < 16; off <<= 1) s += __shfl_xor(s, off);
      float inv = 1.f / s;
      int r = rw + lg * 4 + j;
#pragma unroll
      for (int c = 0; c < 5; ++c) Pl[r][c * 16 + l15] = bfc(p[c] * inv);
      float as = accA[j] * SCALE_ * invT;
      float sg = 1.f / (1.f + __expf(-as));
      float mv = sg * prior[q0 + r] * 0.9f + 0.1f;
      Ml[r][l15] = bfc(mv);
    }
    // NO barrier: PV reads only this wave's own Pl/Ml rows (+ static Vt/AUVt)

    f32x4 accO[4], accAO[4];
#pragma unroll
    for (int c = 0; c < 4; ++c) {
      accO[c] = z4;
      accAO[c] = z4;
    }
#pragma unroll
    for (int kk = 0; kk < 96; kk += 32) {
      bf16x8 ap = *(const bf16x8*)&Pl[rw + l15][kk + lg * 8];
#pragma unroll
      for (int c = 0; c < 4; ++c) {
        bf16x8 bv = *(const bf16x8*)&Vt[c * 16 + l15][kk + lg * 8];
        accO[c] =
            __builtin_amdgcn_mfma_f32_16x16x32_bf16(ap, bv, accO[c], 0, 0, 0);
      }
    }
    {
      bf16x8 am = *(const bf16x8*)&Ml[rw + l15][lg * 8];
#pragma unroll
      for (int c = 0; c < 4; ++c) {
        bf16x8 bv = *(const bf16x8*)&AUVt[c * 16 + l15][lg * 8];
        accAO[c] =
            __builtin_amdgcn_mfma_f32_16x16x32_bf16(am, bv, accAO[c], 0, 0, 0);
      }
    }
    // O tile -> own Pl rows cols 0..63 (Pl P-data dead after PV above)
#pragma unroll
    for (int c = 0; c < 4; ++c)
#pragma unroll
      for (int j = 0; j < 4; ++j) {
        int r = rw + lg * 4 + j;
        Pl[r][c * 16 + l15] = bfc(accO[c][j] + g * accAO[c][j]);
      }
    __syncthreads();  // O tile visible to all
    // coalesced copy Pl[0..63][0..63] -> Ob
#pragma unroll
    for (int i2 = 0; i2 < 2; ++i2) {
      int idx = t + i2 * 256;
      int r = idx >> 3, cg = idx & 7;
      *(int4*)(Ob + (size_t)(b * S_ + q0 + r) * HID_ + h * DH_ + cg * 8) =
          *(const int4*)&Pl[r][cg * 8];
    }
  }
}

// ---------------------------------------------------------------- launcher
extern "C" void kernel_launch(void* const* d_in, const int* in_sizes, int n_in,
                              void* d_out, int out_size, void* d_ws,
                              size_t ws_size, hipStream_t stream) {
  const float* hs = (const float*)d_in[0];
  const float* enc = (const float*)d_in[1];
  const float* au = (const float*)d_in[2];
  const float* Wq = (const float*)d_in[3];
  const float* Wk = (const float*)d_in[4];
  const float* Wv = (const float*)d_in[5];
  const float* Wauk = (const float*)d_in[6];
  const float* Wauv = (const float*)d_in[7];
  const float* Wout = (const float*)d_in[8];
  const float* bout = (const float*)d_in[9];
  const float* temp = (const float*)d_in[10];
  const float* gate = (const float*)d_in[11];
  float* out = (float*)d_out;
  char* ws = (char*)d_ws;

  const size_t szK = (size_t)B_ * KV_ * HID_ * 2;   // 788480
  const size_t szAU = (size_t)B_ * AU_ * HID_ * 2;  // 163840
  const size_t szW640 = (size_t)HID_ * HID_ * 2;    // 819200
  const size_t szW768 = (size_t)HID_ * CROSS_ * 2;  // 983040

  size_t off = 0;
  float* prior = (float*)(ws + off);  off += 16384;
  short* Kbf = (short*)(ws + off);    off += szK;
  short* Vbf = (short*)(ws + off);    off += szK;
  short* AUKbf = (short*)(ws + off);  off += szAU;
  short* AUVbf = (short*)(ws + off);  off += szAU;
  short* Wqt = (short*)(ws + off);    off += szW640;
  short* Wkt = (short*)(ws + off);    off += szW768;
  short* Wvt = (short*)(ws + off);    off += szW768;
  short* Waukt = (short*)(ws + off);  off += szW768;
  short* Wauvt = (short*)(ws + off);  off += szW768;
  short* Woutt = (short*)(ws + off);  off += szW640;
  short* Qbf = (short*)(ws + off);    // 41.94 MB; total ws ~49.5 MB
  short* Abf = Qbf;                   // ALIAS: attn overwrites Q in place
  short* hsb = (short*)d_out;         // d_out head as scratch (dead before
                                      // gemm_out_k writes real output)

  prior_k<<<16, 256, 0, stream>>>(prior);
  wprep_k<<<dim3(10, 12, 6), 256, 0, stream>>>(Wq, Wk, Wv, Wauk, Wauv, Wout,
                                               Wqt, Wkt, Wvt, Waukt, Wauvt,
                                               Woutt);
  cvt_k<<<10240, 256, 0, stream>>>(hs, hsb, (B_ * S_ * HID_) / 8);
  proj4_k<<<dim3(5, 5, 4), 256, 0, stream>>>(enc, au, Wkt, Wvt, Waukt, Wauvt,
                                             Kbf, Vbf, AUKbf, AUVbf);
  gemm_q_k<<<dim3(128, 5), 512, 0, stream>>>(hsb, Wqt, Qbf);
  attn_k<<<dim3(8, HEADS_, B_), 256, 0, stream>>>(Qbf, Kbf, Vbf, AUKbf, AUVbf,
                                                  prior, Abf, temp, gate);
  gemm_out_k<<<dim3(128, 5), 512, 0, stream>>>(Abf, Woutt, out, bout, hs);
}

// Round 7
// 237.006 us; speedup vs baseline: 1.3943x; 1.0041x over previous
//
#include <hip/hip_runtime.h>
#include <hip/hip_bf16.h>

#define B_ 8
#define S_ 4096
#define HID_ 640
#define KV_ 77
#define AU_ 16
#define CROSS_ 768
#define HEADS_ 10
#define DH_ 64
#define SCALE_ 0.125f

using f32x4 = __attribute__((ext_vector_type(4))) float;
using bf16x8 = __attribute__((ext_vector_type(8))) short;

__device__ __forceinline__ short bfc(float f) {
  __hip_bfloat16 h = __float2bfloat16(f);
  return __builtin_bit_cast(short, h);
}

__device__ __forceinline__ void gload16(const void* g, void* lds) {
  __builtin_amdgcn_global_load_lds(
      (const __attribute__((address_space(1))) void*)g,
      (__attribute__((address_space(3))) void*)lds, 16, 0, 0);
}

// ---------------------------------------------------------------- prior table
__global__ __launch_bounds__(256) void prior_k(float* prior) {
  int i = blockIdx.x * 256 + threadIdx.x;
  if (i < S_) {
    int yy = i >> 6, xx = i & 63;
    float lx = -1.f + 2.f * (float)xx / 63.f;
    float ly = -1.f + 2.f * (float)yy / 63.f;
    prior[i] = __expf(-(lx * lx + ly * ly) * (1.0f / 0.605f));
  }
}

// ---------------------------------------------------------------- f32 -> bf16
__global__ __launch_bounds__(256) void cvt_k(const float* in, short* out,
                                             int n8) {
  int i = blockIdx.x * 256 + threadIdx.x;
  if (i >= n8) return;
  const float4 a = *(const float4*)(in + (size_t)i * 8);
  const float4 b = *(const float4*)(in + (size_t)i * 8 + 4);
  bf16x8 v;
  v[0] = bfc(a.x); v[1] = bfc(a.y); v[2] = bfc(a.z); v[3] = bfc(a.w);
  v[4] = bfc(b.x); v[5] = bfc(b.y); v[6] = bfc(b.z); v[7] = bfc(b.w);
  *(bf16x8*)(out + (size_t)i * 8) = v;
}

// ------------------------------------------------- weight transpose + convert
__global__ __launch_bounds__(256) void wprep_k(
    const float* Wq, const float* Wk, const float* Wv, const float* Wauk,
    const float* Wauv, const float* Wout, short* Wqt, short* Wkt, short* Wvt,
    short* Waukt, short* Wauvt, short* Woutt) {
  const float* W;
  short* Wt;
  int K;
  switch (blockIdx.z) {
    case 0: W = Wq;   Wt = Wqt;   K = 640; break;
    case 1: W = Wk;   Wt = Wkt;   K = 768; break;
    case 2: W = Wv;   Wt = Wvt;   K = 768; break;
    case 3: W = Wauk; Wt = Waukt; K = 768; break;
    case 4: W = Wauv; Wt = Wauvt; K = 768; break;
    default: W = Wout; Wt = Woutt; K = 640; break;
  }
  int kt = blockIdx.y * 64, nt = blockIdx.x * 64;
  if (kt >= K) return;
  __shared__ short Tl[64][72];
  const int t = threadIdx.x;
#pragma unroll
  for (int j = 0; j < 16; ++j) {
    int i = t + j * 256;
    int r = i >> 6, c = i & 63;
    Tl[c][r] = bfc(W[(size_t)(kt + r) * 640 + nt + c]);
  }
  __syncthreads();
#pragma unroll
  for (int j = 0; j < 2; ++j) {
    int i = t + j * 256;
    int nl = i >> 3, c = i & 7;
    *(int4*)&Wt[(size_t)(nt + nl) * K + kt + c * 8] = *(int4*)&Tl[nl][c * 8];
  }
}

// ---------------------------------------------- big GEMM, pipelined (R7)
// 256x128 tile, K=640 fixed, BK=32, 20 K-iters, 3-buffer LDS, 2-ahead
// prefetch via global_load_lds; counted vmcnt(3) + raw s_barrier (loads stay
// in flight across barriers); setprio around MFMA cluster.
// Swizzle: row = 64B = 4 slots of 16B; src slot s -> s^(r&3); read
// byteoff = (lg<<4) ^ ((row&3)<<4). Wave read covers 16 full rows -> no
// bank conflicts.
template <bool EPI>
__device__ __forceinline__ void gemm256p(const short* Abf, const short* Bt,
                                         void* Cout, const float* bias,
                                         const float* resid, int N, int m0,
                                         int n0) {
  __shared__ short Al[3 * 8192];  // 3 x [256][32]
  __shared__ short Bl[3 * 4096];  // 3 x [128][32]
  const int t = threadIdx.x;
  const int lane = t & 63;
  const int wave = t >> 6;  // 0..7
  const int l15 = lane & 15, lg = lane >> 4;
  const int wr = (wave >> 1) * 64;
  const int wc = (wave & 1) * 64;

  f32x4 z4 = {0.f, 0.f, 0.f, 0.f};
  f32x4 acc[4][4];
#pragma unroll
  for (int i = 0; i < 4; ++i)
#pragma unroll
    for (int j = 0; j < 4; ++j) acc[i][j] = z4;

  auto stage = [&](int tile, int buf) {
    const int kt = tile * 32;
    short* Ad = &Al[buf * 8192];
    short* Bd = &Bl[buf * 4096];
#pragma unroll
    for (int i = 0; i < 2; ++i) {
      int chunk = wave * 128 + i * 64 + lane;
      int r = chunk >> 2, s = chunk & 3;
      gload16(Abf + (size_t)(m0 + r) * 640 + kt + ((s ^ (r & 3)) << 3),
              Ad + (wave * 128 + i * 64) * 8);
    }
    {
      int chunk = wave * 64 + lane;
      int r = chunk >> 2, s = chunk & 3;
      gload16(Bt + (size_t)(n0 + r) * 640 + kt + ((s ^ (r & 3)) << 3),
              Bd + (wave * 64) * 8);
    }
  };

  // prologue: prefetch tiles 0 and 1
  stage(0, 0);
  stage(1, 1);
  asm volatile("s_waitcnt vmcnt(3)" ::: "memory");  // tile 0 landed
  __builtin_amdgcn_s_barrier();

  int cur = 0, nxt = 2;
  for (int tt = 0; tt < 20; ++tt) {
    const short* Ab = &Al[cur * 8192];
    const short* Bb = &Bl[cur * 4096];
    bf16x8 af[4], bfr[4];
#pragma unroll
    for (int mi = 0; mi < 4; ++mi) {
      int row = wr + mi * 16 + l15;
      af[mi] = *(const bf16x8*)((const char*)(Ab + row * 32) +
                                ((lg << 4) ^ ((row & 3) << 4)));
    }
#pragma unroll
    for (int ni = 0; ni < 4; ++ni) {
      int row = wc + ni * 16 + l15;
      bfr[ni] = *(const bf16x8*)((const char*)(Bb + row * 32) +
                                 ((lg << 4) ^ ((row & 3) << 4)));
    }
    if (tt < 18) stage(tt + 2, nxt);

    __builtin_amdgcn_s_setprio(1);
#pragma unroll
    for (int mi = 0; mi < 4; ++mi)
#pragma unroll
      for (int ni = 0; ni < 4; ++ni)
        acc[mi][ni] = __builtin_amdgcn_mfma_f32_16x16x32_bf16(
            af[mi], bfr[ni], acc[mi][ni], 0, 0, 0);
    __builtin_amdgcn_s_setprio(0);

    if (tt < 18) {
      asm volatile("s_waitcnt vmcnt(3)" ::: "memory");  // next tile landed
    } else if (tt == 18) {
      asm volatile("s_waitcnt vmcnt(0)" ::: "memory");  // last tile landed
    }
    if (tt < 19) __builtin_amdgcn_s_barrier();
    cur = (cur == 2) ? 0 : cur + 1;
    nxt = (nxt == 2) ? 0 : nxt + 1;
  }

  // epilogue
#pragma unroll
  for (int mi = 0; mi < 4; ++mi) {
#pragma unroll
    for (int j = 0; j < 4; ++j) {
      int row = m0 + wr + mi * 16 + lg * 4 + j;
#pragma unroll
      for (int ni = 0; ni < 4; ++ni) {
        int col = n0 + wc + ni * 16 + l15;
        size_t idx = (size_t)row * N + col;
        float val = acc[mi][ni][j];
        if (EPI) {
          ((float*)Cout)[idx] = val + bias[col] + resid[idx];
        } else {
          ((short*)Cout)[idx] = bfc(val);
        }
      }
    }
  }
}

__global__ __launch_bounds__(512, 4) void gemm_q_k(const short* A,
                                                   const short* Bt, short* C) {
  gemm256p<false>(A, Bt, C, nullptr, nullptr, HID_, blockIdx.x * 256,
                  blockIdx.y * 128);
}

__global__ __launch_bounds__(512, 4) void gemm_out_k(const short* A,
                                                     const short* Bt, float* C,
                                                     const float* bias,
                                                     const float* resid) {
  gemm256p<true>(A, Bt, C, bias, resid, HID_, blockIdx.x * 256,
                 blockIdx.y * 128);
}

// ---------------------------------------------------------------- small GEMM
__device__ __forceinline__ void gemm_small(const float* A32, const short* Bt,
                                           short* Cout, int M, int K, int N,
                                           int m0, int n0) {
  __shared__ short Al[128][72];
  __shared__ short Bl[128][72];
  const int t = threadIdx.x;
  const int lane = t & 63;
  const int wave = t >> 6;
  const int l15 = lane & 15, lg = lane >> 4;
  const int wr = (wave >> 1) * 64, wc = (wave & 1) * 64;

  f32x4 z4 = {0.f, 0.f, 0.f, 0.f};
  f32x4 acc[4][4];
#pragma unroll
  for (int i = 0; i < 4; ++i)
#pragma unroll
    for (int j = 0; j < 4; ++j) acc[i][j] = z4;

  for (int k0 = 0; k0 < K; k0 += 64) {
#pragma unroll
    for (int j = 0; j < 8; ++j) {
      int i = t + j * 256;
      int r = i >> 4, q = i & 15;
      int row = m0 + r;
      float4 v = {0.f, 0.f, 0.f, 0.f};
      if (row < M) v = *(const float4*)(A32 + (size_t)row * K + k0 + q * 4);
      short4 s;
      s.x = bfc(v.x);
      s.y = bfc(v.y);
      s.z = bfc(v.z);
      s.w = bfc(v.w);
      *(short4*)&Al[r][q * 4] = s;
    }
#pragma unroll
    for (int j = 0; j < 4; ++j) {
      int i = t + j * 256;
      int row = i >> 3, c = i & 7;
      *(int4*)&Bl[row][c * 8] =
          *(const int4*)(Bt + (size_t)(n0 + row) * K + k0 + c * 8);
    }
    __syncthreads();
#pragma unroll
    for (int ks = 0; ks < 64; ks += 32) {
      bf16x8 af[4], bfr[4];
#pragma unroll
      for (int mi = 0; mi < 4; ++mi)
        af[mi] = *(const bf16x8*)&Al[wr + mi * 16 + l15][ks + lg * 8];
#pragma unroll
      for (int ni = 0; ni < 4; ++ni)
        bfr[ni] = *(const bf16x8*)&Bl[wc + ni * 16 + l15][ks + lg * 8];
#pragma unroll
      for (int mi = 0; mi < 4; ++mi)
#pragma unroll
        for (int ni = 0; ni < 4; ++ni)
          acc[mi][ni] = __builtin_amdgcn_mfma_f32_16x16x32_bf16(
              af[mi], bfr[ni], acc[mi][ni], 0, 0, 0);
    }
    __syncthreads();
  }
#pragma unroll
  for (int mi = 0; mi < 4; ++mi) {
#pragma unroll
    for (int j = 0; j < 4; ++j) {
      int row = m0 + wr + mi * 16 + lg * 4 + j;
      if (row >= M) continue;
#pragma unroll
      for (int ni = 0; ni < 4; ++ni) {
        int col = n0 + wc + ni * 16 + l15;
        Cout[(size_t)row * N + col] = bfc(acc[mi][ni][j]);
      }
    }
  }
}

__global__ __launch_bounds__(256) void proj4_k(const float* enc,
                                               const float* au,
                                               const short* Wkt,
                                               const short* Wvt,
                                               const short* Waukt,
                                               const short* Wauvt, short* Kb,
                                               short* Vb, short* AKb,
                                               short* AVb) {
  int z = blockIdx.z;
  const float* A = (z < 2) ? enc : au;
  const short* Bt = (z == 0) ? Wkt : (z == 1) ? Wvt : (z == 2) ? Waukt : Wauvt;
  short* O = (z == 0) ? Kb : (z == 1) ? Vb : (z == 2) ? AKb : AVb;
  int M = (z < 2) ? (B_ * KV_) : (B_ * AU_);
  if ((int)blockIdx.x * 128 >= M) return;
  gemm_small(A, Bt, O, M, CROSS_, HID_, blockIdx.x * 128, blockIdx.y * 128);
}

// ---------------------------------------------------------------- attention
// one block per (512-row q-chunk, h, b); K/V/AU staged ONCE, 8-iter Q loop.
// Ob may alias Qb (in-place, race-free as analyzed in R6).
__global__ __launch_bounds__(256) void attn_k(const short* Qb, const short* Kb,
                                              const short* Vb, const short* AKb,
                                              const short* AVb,
                                              const float* prior, short* Ob,
                                              const float* temp,
                                              const float* gate) {
  __shared__ short Qt[64 * 64];   // linear, XOR-swizzled (gload16 dest)
  __shared__ short Kl[80][72];
  __shared__ short Vt[64][104];
  __shared__ short Pl[64][104];
  __shared__ short AUKl[16][72];
  __shared__ short AUVt[64][40];
  __shared__ short Ml[64][40];

  const int t = threadIdx.x;
  const int lane = t & 63, wave = t >> 6;
  const int l15 = lane & 15, lg = lane >> 4;
  const int qbase = blockIdx.x * 512;
  const int h = blockIdx.y;
  const int b = blockIdx.z;
  const int rw = wave * 16;
  f32x4 z4 = {0.f, 0.f, 0.f, 0.f};

  for (int i = t; i < 64 * 27; i += 256) {
    int r = i / 27, c = i - r * 27;
    Vt[r][77 + c] = 0;
  }
  for (int i = t; i < 64 * 8; i += 256) {
    int r = i >> 3, c = i & 7;
    *(int*)&Pl[r][80 + c * 2] = 0;
  }
  for (int i = t; i < 64 * 12; i += 256) {
    int r = i / 12, c = i - r * 12;
    *(int*)&AUVt[r][16 + c * 2] = 0;
  }
  for (int i = t; i < 64 * 12; i += 256) {
    int r = i / 12, c = i - r * 12;
    *(int*)&Ml[r][16 + c * 2] = 0;
  }
#pragma unroll
  for (int j = 0; j < 3; ++j) {
    int i = t + j * 256;
    if (i < KV_ * 8) {
      int r = i >> 3, c8 = i & 7;
      *(int4*)&Kl[r][c8 * 8] =
          *(const int4*)(Kb + (size_t)(b * KV_ + r) * HID_ + h * DH_ + c8 * 8);
    }
  }
  for (int i = t; i < KV_ * DH_; i += 256) {
    int d = i & 63, kv = i >> 6;
    Vt[d][kv] = Vb[(size_t)(b * KV_ + kv) * HID_ + h * DH_ + d];
  }
  if (t < AU_ * 8) {
    int r = t >> 3, c8 = t & 7;
    *(int4*)&AUKl[r][c8 * 8] =
        *(const int4*)(AKb + (size_t)(b * AU_ + r) * HID_ + h * DH_ + c8 * 8);
  }
  for (int i = t; i < AU_ * DH_; i += 256) {
    int d = i & 63, a = i >> 6;
    AUVt[d][a] = AVb[(size_t)(b * AU_ + a) * HID_ + h * DH_ + d];
  }

  const float invT = 1.f / (fabsf(temp[0]) + 1e-6f);
  const float g = gate[0];  // AU_SCALE = 1

  for (int qi = 0; qi < 8; ++qi) {
    const int q0 = qbase + qi * 64;
#pragma unroll
    for (int i2 = 0; i2 < 2; ++i2) {
      int chunk = wave * 128 + i2 * 64 + lane;
      int r = chunk >> 3, s = chunk & 7;
      const short* src = Qb + (size_t)(b * S_ + q0 + r) * HID_ + h * DH_ +
                         ((s ^ (r & 7)) << 3);
      gload16(src, Qt + (wave * 128 + i2 * 64) * 8);
    }
    __syncthreads();

    f32x4 accS[5], accA = z4;
#pragma unroll
    for (int c = 0; c < 5; ++c) accS[c] = z4;
#pragma unroll
    for (int ks = 0; ks < 2; ++ks) {
      const char* qrow = (const char*)(Qt + (rw + l15) * 64);
      bf16x8 aq =
          *(const bf16x8*)(qrow + ((ks * 64 + lg * 16) ^ ((l15 & 7) << 4)));
#pragma unroll
      for (int c = 0; c < 5; ++c) {
        bf16x8 bk = *(const bf16x8*)&Kl[c * 16 + l15][ks * 32 + lg * 8];
        accS[c] =
            __builtin_amdgcn_mfma_f32_16x16x32_bf16(aq, bk, accS[c], 0, 0, 0);
      }
      bf16x8 ba = *(const bf16x8*)&AUKl[l15][ks * 32 + lg * 8];
      accA = __builtin_amdgcn_mfma_f32_16x16x32_bf16(aq, ba, accA, 0, 0, 0);
    }

#pragma unroll
    for (int j = 0; j < 4; ++j) {
      float v[5];
      float m = -1e30f;
#pragma unroll
      for (int c = 0; c < 5; ++c) {
        int col = c * 16 + l15;
        v[c] = (col < KV_) ? accS[c][j] * SCALE_ : -1e30f;
        m = fmaxf(m, v[c]);
      }
#pragma unroll
      for (int off = 1; off < 16; off <<= 1) m = fmaxf(m, __shfl_xor(m, off));
      float p[5];
      float s = 0.f;
#pragma unroll
      for (int c = 0; c < 5; ++c) {
        p[c] = (v[c] > -1e29f) ? __expf(v[c] - m) : 0.f;
        s += p[c];
      }
#pragma unroll
      for (int off = 1; off < 16; off <<= 1) s += __shfl_xor(s, off);
      float inv = 1.f / s;
      int r = rw + lg * 4 + j;
#pragma unroll
      for (int c = 0; c < 5; ++c) Pl[r][c * 16 + l15] = bfc(p[c] * inv);
      float as = accA[j] * SCALE_ * invT;
      float sg = 1.f / (1.f + __expf(-as));
      float mv = sg * prior[q0 + r] * 0.9f + 0.1f;
      Ml[r][l15] = bfc(mv);
    }

    f32x4 accO[4], accAO[4];
#pragma unroll
    for (int c = 0; c < 4; ++c) {
      accO[c] = z4;
      accAO[c] = z4;
    }
#pragma unroll
    for (int kk = 0; kk < 96; kk += 32) {
      bf16x8 ap = *(const bf16x8*)&Pl[rw + l15][kk + lg * 8];
#pragma unroll
      for (int c = 0; c < 4; ++c) {
        bf16x8 bv = *(const bf16x8*)&Vt[c * 16 + l15][kk + lg * 8];
        accO[c] =
            __builtin_amdgcn_mfma_f32_16x16x32_bf16(ap, bv, accO[c], 0, 0, 0);
      }
    }
    {
      bf16x8 am = *(const bf16x8*)&Ml[rw + l15][lg * 8];
#pragma unroll
      for (int c = 0; c < 4; ++c) {
        bf16x8 bv = *(const bf16x8*)&AUVt[c * 16 + l15][lg * 8];
        accAO[c] =
            __builtin_amdgcn_mfma_f32_16x16x32_bf16(am, bv, accAO[c], 0, 0, 0);
      }
    }
#pragma unroll
    for (int c = 0; c < 4; ++c)
#pragma unroll
      for (int j = 0; j < 4; ++j) {
        int r = rw + lg * 4 + j;
        Pl[r][c * 16 + l15] = bfc(accO[c][j] + g * accAO[c][j]);
      }
    __syncthreads();
#pragma unroll
    for (int i2 = 0; i2 < 2; ++i2) {
      int idx = t + i2 * 256;
      int r = idx >> 3, cg = idx & 7;
      *(int4*)(Ob + (size_t)(b * S_ + q0 + r) * HID_ + h * DH_ + cg * 8) =
          *(const int4*)&Pl[r][cg * 8];
    }
  }
}

// ---------------------------------------------------------------- launcher
extern "C" void kernel_launch(void* const* d_in, const int* in_sizes, int n_in,
                              void* d_out, int out_size, void* d_ws,
                              size_t ws_size, hipStream_t stream) {
  const float* hs = (const float*)d_in[0];
  const float* enc = (const float*)d_in[1];
  const float* au = (const float*)d_in[2];
  const float* Wq = (const float*)d_in[3];
  const float* Wk = (const float*)d_in[4];
  const float* Wv = (const float*)d_in[5];
  const float* Wauk = (const float*)d_in[6];
  const float* Wauv = (const float*)d_in[7];
  const float* Wout = (const float*)d_in[8];
  const float* bout = (const float*)d_in[9];
  const float* temp = (const float*)d_in[10];
  const float* gate = (const float*)d_in[11];
  float* out = (float*)d_out;
  char* ws = (char*)d_ws;

  const size_t szK = (size_t)B_ * KV_ * HID_ * 2;   // 788480
  const size_t szAU = (size_t)B_ * AU_ * HID_ * 2;  // 163840
  const size_t szW640 = (size_t)HID_ * HID_ * 2;    // 819200
  const size_t szW768 = (size_t)HID_ * CROSS_ * 2;  // 983040

  size_t off = 0;
  float* prior = (float*)(ws + off);  off += 16384;
  short* Kbf = (short*)(ws + off);    off += szK;
  short* Vbf = (short*)(ws + off);    off += szK;
  short* AUKbf = (short*)(ws + off);  off += szAU;
  short* AUVbf = (short*)(ws + off);  off += szAU;
  short* Wqt = (short*)(ws + off);    off += szW640;
  short* Wkt = (short*)(ws + off);    off += szW768;
  short* Wvt = (short*)(ws + off);    off += szW768;
  short* Waukt = (short*)(ws + off);  off += szW768;
  short* Wauvt = (short*)(ws + off);  off += szW768;
  short* Woutt = (short*)(ws + off);  off += szW640;
  short* Qbf = (short*)(ws + off);    // 41.94 MB; total ws ~49.5 MB
  short* Abf = Qbf;                   // ALIAS: attn overwrites Q in place
  short* hsb = (short*)d_out;         // d_out head as scratch (dead before
                                      // gemm_out_k writes real output)

  prior_k<<<16, 256, 0, stream>>>(prior);
  wprep_k<<<dim3(10, 12, 6), 256, 0, stream>>>(Wq, Wk, Wv, Wauk, Wauv, Wout,
                                               Wqt, Wkt, Wvt, Waukt, Wauvt,
                                               Woutt);
  cvt_k<<<10240, 256, 0, stream>>>(hs, hsb, (B_ * S_ * HID_) / 8);
  proj4_k<<<dim3(5, 5, 4), 256, 0, stream>>>(enc, au, Wkt, Wvt, Waukt, Wauvt,
                                             Kbf, Vbf, AUKbf, AUVbf);
  gemm_q_k<<<dim3(128, 5), 512, 0, stream>>>(hsb, Wqt, Qbf);
  attn_k<<<dim3(8, HEADS_, B_), 256, 0, stream>>>(Qbf, Kbf, Vbf, AUKbf, AUVbf,
                                                  prior, Abf, temp, gate);
  gemm_out_k<<<dim3(128, 5), 512, 0, stream>>>(Abf, Woutt, out, bout, hs);
}